// Round 2
// baseline (1386.622 us; speedup 1.0000x reference)
//
#include <hip/hip_runtime.h>
#include <math.h>

// ---------------------------------------------------------------------------
// CSAttention forward, MI355X. GEMMs via split-bf16 (hi/lo) 3-MFMA emulation:
//   A*B ~= Ah*Bh + Al*Bh + Ah*Bl   (fp32 accumulate, ~16 mantissa bits)
// Layout: token maps (b, h*64+w, c) row-major, C=256, B=16.
// R5: edge_conv factorized into edge_gemm9 + edge_combine.
// R6: global_load_lds staging (regressed: single-buffer exposed load latency
//     at each barrier -- vmcnt(0) drain per K-step, no overlap).
// R7: T3 "minimum 2-phase" double-buffered pipeline:
//     - all 4 LDS operand buffers double-buffered (64 KB, 2 blocks/CU);
//     - STAGE(t+1) issued at top of iteration, COMPUTE(t), ONE barrier --
//       implicit vmcnt(0) lands after the 48-MFMA cluster, latency hidden;
//     - fp32-A paths (gemm3 x, gemmf BLD) split T14-style: float4 loads
//       issued before MFMA, split2+ds_write after it;
//     - A-split LDS writes re-mapped chunk-linear (thread t -> 16B chunks
//       t, t+256): store bank-starts cover all 8 slots, conflict-free.
// ---------------------------------------------------------------------------

#define CHUNK_B 4
#define CHUNK_TOK (CHUNK_B * 4096)   // 16384 tokens per chunk
#define KS 32                        // LDS k-slice width (elements), 64B rows

typedef __attribute__((ext_vector_type(8))) short short8;
typedef __attribute__((ext_vector_type(8))) unsigned short ushort8;
typedef __attribute__((ext_vector_type(4))) float f32x4;

__device__ __forceinline__ ushort f2bf(float f) {
    union { float f; unsigned u; } v; v.f = f;
    unsigned r = v.u + 0x7fff + ((v.u >> 16) & 1);
    return (ushort)(r >> 16);
}
__device__ __forceinline__ float bf2f(ushort h) {
    union { unsigned u; float f; } v; v.u = ((unsigned)h) << 16; return v.f;
}
__device__ __forceinline__ void split2(float v, ushort& h, ushort& l) {
    h = f2bf(v);
    l = f2bf(v - bf2f(h));
}

// async 16B/lane global -> LDS (wave-uniform LDS base, per-lane global addr)
__device__ __forceinline__ void gld16(const ushort* g, ushort* l) {
    __builtin_amdgcn_global_load_lds(
        (const __attribute__((address_space(1))) unsigned int*)g,
        (__attribute__((address_space(3))) unsigned int*)l,
        16, 0, 0);
}

// ---------------- weight pre-split kernels ---------------------------------
__global__ __launch_bounds__(256) void split_w_kmajor(
    const float* __restrict__ W, ushort* __restrict__ Th, ushort* __restrict__ Tl, int nmats)
{
    const int idx = blockIdx.x * 256 + threadIdx.x;
    if (idx >= nmats * 65536) return;
    const int mat = idx >> 16, r = idx & 65535;
    const int n = r >> 8, k = r & 255;
    const float v = W[(size_t)mat * 65536 + k * 256 + n];
    ushort h, l; split2(v, h, l);
    Th[idx] = h; Tl[idx] = l;
}
__global__ __launch_bounds__(256) void split_w_nmajor(
    const float* __restrict__ W, ushort* __restrict__ Th, ushort* __restrict__ Tl, int total)
{
    const int idx = blockIdx.x * 256 + threadIdx.x;
    if (idx >= total) return;
    ushort h, l; split2(W[idx], h, l);
    Th[idx] = h; Tl[idx] = l;
}

// ---------------- MFMA GEMM core pieces (macros for reuse) -----------------
#define GEMM_DECLS                                                            \
    __shared__ ushort Ah[2][128 * KS], Al[2][128 * KS];                       \
    __shared__ ushort Bh[2][128 * KS], Bl[2][128 * KS];                       \
    const int tid = threadIdx.x;                                              \
    const int wave = tid >> 6, lane = tid & 63;                               \
    const int quad = lane >> 4, l16 = lane & 15;                              \
    const int wr = (wave >> 1) * 64, wc = (wave & 1) * 64;                    \
    f32x4 acc[4][4];                                                          \
    _Pragma("unroll") for (int i = 0; i < 4; i++)                             \
        _Pragma("unroll") for (int j = 0; j < 4; j++)                         \
            acc[i][j] = (f32x4){0.f, 0.f, 0.f, 0.f};

// Async stage one 128xKS ushort buffer from row-major [row][strideE] source.
// Wave w, sub-issue jj covers rows (32w + 16jj .. +15); lane -> row base+l/4,
// k-bytes (l%4)*16. LDS dest linear: base + wave*1024 + jj*512 (ushorts).
#define STAGE_GLD(dstbuf, srcp, strideE, rowbase, k0e)                        \
    _Pragma("unroll") for (int jj = 0; jj < 2; jj++) {                        \
        const int rr = (wave << 5) + (jj << 4) + (lane >> 2);                 \
        gld16((srcp) + (size_t)((rowbase) + rr) * (strideE) + (k0e) + ((lane & 3) << 3), \
              (dstbuf) + (wave << 10) + (jj << 9));                           \
    }

// fp32-A staging, deferred-split. Thread tid owns 16B chunks (tid, tid+256)
// of the [128][32] buffer: row = chunk>>2, kcols (chunk&3)*8..+7.
// Store bank-start = (chunk*4)%32 -> all 8 slots covered evenly (no conflict).
#define A_LOAD(Aptr, kk)                                                      \
    {                                                                         \
        const int r0 = tid >> 2, kq = (tid & 3) * 8;                          \
        const float* p0 = (Aptr) + (size_t)(m0 + r0) * 256 + (kk) + kq;       \
        const float* p1 = p0 + (size_t)64 * 256;                              \
        va[0] = *(const float4*)p0; va[1] = *(const float4*)(p0 + 4);         \
        va[2] = *(const float4*)p1; va[3] = *(const float4*)(p1 + 4);         \
    }

#define A_SPLIT_WRITE(AhD, AlD)                                               \
    _Pragma("unroll") for (int cc = 0; cc < 2; cc++) {                        \
        ushort8 h, l; ushort hh, ll;                                          \
        const float4 v0 = va[cc * 2], v1 = va[cc * 2 + 1];                    \
        split2(v0.x, hh, ll); h[0] = hh; l[0] = ll;                           \
        split2(v0.y, hh, ll); h[1] = hh; l[1] = ll;                           \
        split2(v0.z, hh, ll); h[2] = hh; l[2] = ll;                           \
        split2(v0.w, hh, ll); h[3] = hh; l[3] = ll;                           \
        split2(v1.x, hh, ll); h[4] = hh; l[4] = ll;                           \
        split2(v1.y, hh, ll); h[5] = hh; l[5] = ll;                           \
        split2(v1.z, hh, ll); h[6] = hh; l[6] = ll;                           \
        split2(v1.w, hh, ll); h[7] = hh; l[7] = ll;                           \
        const int chw = tid + cc * 256;                                       \
        *(ushort8*)&(AhD)[chw * 8] = h;                                       \
        *(ushort8*)&(AlD)[chw * 8] = l;                                       \
    }

#define GEMM_COMPUTE(cb)                                                      \
    {                                                                         \
        short8 afh[4], afl[4], bfh[4], bfl[4];                                \
        _Pragma("unroll") for (int i = 0; i < 4; i++) {                       \
            const int ro = (wr + i * 16 + l16) * KS + quad * 8;               \
            afh[i] = *(const short8*)&Ah[cb][ro];                             \
            afl[i] = *(const short8*)&Al[cb][ro];                             \
        }                                                                     \
        _Pragma("unroll") for (int j = 0; j < 4; j++) {                       \
            const int no = (wc + j * 16 + l16) * KS + quad * 8;               \
            bfh[j] = *(const short8*)&Bh[cb][no];                             \
            bfl[j] = *(const short8*)&Bl[cb][no];                             \
        }                                                                     \
        _Pragma("unroll") for (int i = 0; i < 4; i++)                         \
            _Pragma("unroll") for (int j = 0; j < 4; j++) {                   \
                acc[i][j] = __builtin_amdgcn_mfma_f32_16x16x32_bf16(          \
                    afh[i], bfh[j], acc[i][j], 0, 0, 0);                      \
                acc[i][j] = __builtin_amdgcn_mfma_f32_16x16x32_bf16(          \
                    afl[i], bfh[j], acc[i][j], 0, 0, 0);                      \
                acc[i][j] = __builtin_amdgcn_mfma_f32_16x16x32_bf16(          \
                    afh[i], bfl[j], acc[i][j], 0, 0, 0);                      \
            }                                                                 \
    }

// ---------- fused 3-matrix GEMM (Q,K,V or axial q,k,v): grid (M/128, 6) -----
__global__ __launch_bounds__(256, 2) void gemm3_mfma(
    const float* __restrict__ A,
    const ushort* __restrict__ Wth, const ushort* __restrict__ Wtl,
    const float* __restrict__ b0, const float* __restrict__ b1, const float* __restrict__ b2,
    float* __restrict__ O0, float* __restrict__ O1, float* __restrict__ O2)
{
    const int m0 = blockIdx.x * 128;
    const int mat = blockIdx.y >> 1;
    const int col0 = (blockIdx.y & 1) * 128;
    const ushort* wth = Wth + (size_t)mat * 65536 + (size_t)col0 * 256;
    const ushort* wtl = Wtl + (size_t)mat * 65536 + (size_t)col0 * 256;
    GEMM_DECLS
    float4 va[4];
    // prologue: stage tile 0 into buffer 0
    STAGE_GLD(Bh[0], wth, 256, 0, 0)
    STAGE_GLD(Bl[0], wtl, 256, 0, 0)
    A_LOAD(A, 0)
    A_SPLIT_WRITE(Ah[0], Al[0])
    __syncthreads();
#pragma unroll
    for (int t = 0; t < 8; ++t) {
        const int cur = t & 1, nxt = cur ^ 1;
        if (t < 7) {
            STAGE_GLD(Bh[nxt], wth, 256, 0, (t + 1) * 32)
            STAGE_GLD(Bl[nxt], wtl, 256, 0, (t + 1) * 32)
            A_LOAD(A, (t + 1) * 32)
        }
        GEMM_COMPUTE(cur)
        if (t < 7) { A_SPLIT_WRITE(Ah[nxt], Al[nxt]) }
        __syncthreads();
    }
    const float* bias = (mat == 0) ? b0 : (mat == 1) ? b1 : b2;
    float* O = (mat == 0) ? O0 : (mat == 1) ? O1 : O2;
#pragma unroll
    for (int j = 0; j < 4; j++) {
        const int col = col0 + wc + j * 16 + l16;
        const float bj = bias[col];
#pragma unroll
        for (int i = 0; i < 4; i++) {
            const int rbase = m0 + wr + i * 16 + quad * 4;
#pragma unroll
            for (int r = 0; r < 4; r++)
                O[(size_t)(rbase + r) * 256 + col] = acc[i][j][r] + bj;
        }
    }
}

// ---------- out-projection GEMM with fused blend: grid (M/128, 2) -----------
// A is pre-split (ctx hi/lo from win_attn) -> fully async staging.
__global__ __launch_bounds__(256, 2) void gemmp_mfma(
    const ushort* __restrict__ AgH, const ushort* __restrict__ AgL,
    const ushort* __restrict__ Wth, const ushort* __restrict__ Wtl,
    const float* __restrict__ bias,
    float* __restrict__ Sout, int store_s,
    float* __restrict__ Blnd, const float* __restrict__ wts, int scale_idx, int blend_init,
    int row_off)
{
    const int m0 = blockIdx.x * 128;
    const int col0 = blockIdx.y * 128;
    const ushort* wth = Wth + (size_t)col0 * 256;
    const ushort* wtl = Wtl + (size_t)col0 * 256;
    GEMM_DECLS
    STAGE_GLD(Ah[0], AgH, 256, m0, 0)
    STAGE_GLD(Al[0], AgL, 256, m0, 0)
    STAGE_GLD(Bh[0], wth, 256, 0, 0)
    STAGE_GLD(Bl[0], wtl, 256, 0, 0)
    __syncthreads();
#pragma unroll
    for (int t = 0; t < 8; ++t) {
        const int cur = t & 1, nxt = cur ^ 1;
        if (t < 7) {
            STAGE_GLD(Ah[nxt], AgH, 256, m0, (t + 1) * 32)
            STAGE_GLD(Al[nxt], AgL, 256, m0, (t + 1) * 32)
            STAGE_GLD(Bh[nxt], wth, 256, 0, (t + 1) * 32)
            STAGE_GLD(Bl[nxt], wtl, 256, 0, (t + 1) * 32)
        }
        GEMM_COMPUTE(cur)
        __syncthreads();
    }
#pragma unroll
    for (int i = 0; i < 4; i++) {
        const int rbase = m0 + wr + i * 16 + quad * 4;
#pragma unroll
        for (int r = 0; r < 4; r++) {
            const size_t grow = (size_t)row_off + rbase + r;
            const float wt = wts[grow * 3 + scale_idx];
#pragma unroll
            for (int j = 0; j < 4; j++) {
                const int col = col0 + wc + j * 16 + l16;
                const float v = acc[i][j][r] + bias[col];
                if (store_s) Sout[grow * 256 + col] = v;
                float* bp = Blnd + grow * 256 + col;
                if (blend_init) *bp = wt * v;
                else            *bp = *bp + wt * v;
            }
        }
    }
}

// ---------- final squeeze: OUT = [UP | BL] @ sq_w^T + sq_b, K=512 -----------
// UP half pre-split (from upsample) -> async; BLD half fp32 deferred split.
__global__ __launch_bounds__(256, 2) void gemmf_mfma(
    const ushort* __restrict__ UPH, const ushort* __restrict__ UPL,
    const float* __restrict__ BLD,
    const ushort* __restrict__ Wth, const ushort* __restrict__ Wtl,
    const float* __restrict__ SQB, float* __restrict__ OUT)
{
    const int m0 = blockIdx.x * 128;
    const int col0 = blockIdx.y * 128;
    const ushort* wth = Wth + (size_t)col0 * 512;
    const ushort* wtl = Wtl + (size_t)col0 * 512;
    GEMM_DECLS
    float4 va[4];
    STAGE_GLD(Bh[0], wth, 512, 0, 0)
    STAGE_GLD(Bl[0], wtl, 512, 0, 0)
    STAGE_GLD(Ah[0], UPH, 256, m0, 0)
    STAGE_GLD(Al[0], UPL, 256, m0, 0)
    __syncthreads();
#pragma unroll
    for (int t = 0; t < 16; ++t) {
        const int cur = t & 1, nxt = cur ^ 1;
        const int k1 = (t + 1) * 32;
        if (t < 15) {
            STAGE_GLD(Bh[nxt], wth, 512, 0, k1)
            STAGE_GLD(Bl[nxt], wtl, 512, 0, k1)
            if (k1 < 256) {
                STAGE_GLD(Ah[nxt], UPH, 256, m0, k1)
                STAGE_GLD(Al[nxt], UPL, 256, m0, k1)
            } else {
                A_LOAD(BLD, (k1 & 255))
            }
        }
        GEMM_COMPUTE(cur)
        if (t < 15 && k1 >= 256) { A_SPLIT_WRITE(Ah[nxt], Al[nxt]) }
        __syncthreads();
    }
#pragma unroll
    for (int j = 0; j < 4; j++) {
        const int col = col0 + wc + j * 16 + l16;
        const float bj = SQB[col];
#pragma unroll
        for (int i = 0; i < 4; i++) {
            const int rbase = m0 + wr + i * 16 + quad * 4;
#pragma unroll
            for (int r = 0; r < 4; r++)
                OUT[(size_t)(rbase + r) * 256 + col] = acc[i][j][r] + bj;
        }
    }
}

// ----------------- windowed multi-head attention (per window) ---------------
// Emits ctx pre-split (hi/lo) so the out-projection can stage A async.
template <int WS, int NH>
__global__ __launch_bounds__(256) void win_attn(
    const float* __restrict__ Q, const float* __restrict__ K,
    const float* __restrict__ V, ushort* __restrict__ CTXh, ushort* __restrict__ CTXl)
{
    constexpr int WIN = WS * WS;
    constexpr int NW = 64 / WS;
    constexpr int CW = NH * 32;
    __shared__ float qs[WIN][CW + 4], ks[WIN][CW + 4], vs[WIN][CW + 4];
    __shared__ float sc[NH][WIN][WIN + 1];
    const int tid = threadIdx.x;
    const int wid = blockIdx.x;
    const int b = wid / (NW * NW);
    const int rem = wid % (NW * NW);
    const int p = rem / NW, q = rem % NW;
    const int h0 = blockIdx.y * NH;

    for (int idx = tid; idx < WIN * CW; idx += 256) {
        const int i = idx / CW;
        const int cc = idx % CW;
        const int ti = i / WS, tj = i % WS;
        const size_t g = ((size_t)(b * 4096 + (p * WS + ti) * 64 + (q * WS + tj))) * 256 + h0 * 32 + cc;
        qs[i][cc] = Q[g]; ks[i][cc] = K[g]; vs[i][cc] = V[g];
    }
    __syncthreads();
    const float scale = 0.17677669529663687f;  // 1/sqrt(32)
    for (int idx = tid; idx < NH * WIN * WIN; idx += 256) {
        const int hl = idx / (WIN * WIN);
        const int r = idx % (WIN * WIN);
        const int i = r / WIN, j = r % WIN;
        const int co = hl * 32;
        float s = 0.f;
#pragma unroll
        for (int d = 0; d < 32; d++) s += qs[i][co + d] * ks[j][co + d];
        sc[hl][i][j] = s * scale;
    }
    __syncthreads();
    if (tid < NH * WIN) {
        const int hl = tid / WIN, i = tid % WIN;
        float mx = -3.4e38f;
        for (int j = 0; j < WIN; j++) mx = fmaxf(mx, sc[hl][i][j]);
        float sum = 0.f;
        for (int j = 0; j < WIN; j++) {
            float e = __expf(sc[hl][i][j] - mx);
            sc[hl][i][j] = e; sum += e;
        }
        const float inv = 1.f / sum;
        for (int j = 0; j < WIN; j++) sc[hl][i][j] *= inv;
    }
    __syncthreads();
    for (int idx = tid; idx < WIN * CW; idx += 256) {
        const int i = idx / CW;
        const int cc = idx % CW;
        const int hl = cc >> 5;
        float s = 0.f;
        for (int j = 0; j < WIN; j++) s += sc[hl][i][j] * vs[j][cc];
        const int ti = i / WS, tj = i % WS;
        const size_t g = ((size_t)(b * 4096 + (p * WS + ti) * 64 + (q * WS + tj))) * 256 + h0 * 32 + cc;
        ushort hh, ll; split2(s, hh, ll);
        CTXh[g] = hh; CTXl[g] = ll;
    }
}

// -------- edge conv phase 1: y[p][t] = sum_c x[p][c] * ew[c][t] -------------
__global__ __launch_bounds__(256) void edge_gemm9(
    const float* __restrict__ x, const float* __restrict__ ew, float* __restrict__ ytmp)
{
    __shared__ float wsm[2304];   // ew[c*9 + t]
    const int tid = threadIdx.x;
    for (int i = tid; i < 2304; i += 256) wsm[i] = ew[i];
    __syncthreads();
    const int wave = tid >> 6, lane = tid & 63;
    const int p = blockIdx.x * 4 + wave;            // pixel index 0..65535
    const float4 xv = *(const float4*)(x + (size_t)p * 256 + lane * 4);
    float acc[9];
#pragma unroll
    for (int t = 0; t < 9; t++) acc[t] = 0.f;
    const float xs[4] = {xv.x, xv.y, xv.z, xv.w};
#pragma unroll
    for (int i = 0; i < 4; i++) {
        const int c = lane * 4 + i;
#pragma unroll
        for (int t = 0; t < 9; t++)
            acc[t] = fmaf(xs[i], wsm[c * 9 + t], acc[t]);
    }
#pragma unroll
    for (int t = 0; t < 9; t++) {
#pragma unroll
        for (int off = 1; off < 64; off <<= 1)
            acc[t] += __shfl_xor(acc[t], off);
    }
    if (lane < 9) {
        float v = acc[0];
        switch (lane) {
            case 1: v = acc[1]; break; case 2: v = acc[2]; break;
            case 3: v = acc[3]; break; case 4: v = acc[4]; break;
            case 5: v = acc[5]; break; case 6: v = acc[6]; break;
            case 7: v = acc[7]; break; case 8: v = acc[8]; break;
            default: break;
        }
        ytmp[(size_t)p * 9 + lane] = v;
    }
}

// -------- edge conv phase 2: edge[h,w] = |sum_t y[h+dh,w+dw][t]| ------------
__global__ __launch_bounds__(256) void edge_combine(
    const float* __restrict__ ytmp, float* __restrict__ edge)
{
    const int idx = blockIdx.x * 256 + threadIdx.x;   // 0..65535
    const int b = idx >> 12, rem = idx & 4095, h = rem >> 6, w = rem & 63;
    float s = 0.f;
#pragma unroll
    for (int kh = 0; kh < 3; kh++) {
        const int hh = h + kh - 1;
        if ((unsigned)hh > 63u) continue;
#pragma unroll
        for (int kw = 0; kw < 3; kw++) {
            const int ww = w + kw - 1;
            if ((unsigned)ww > 63u) continue;
            s += ytmp[((size_t)b * 4096 + hh * 64 + ww) * 9 + kh * 3 + kw];
        }
    }
    edge[idx] = fabsf(s);
}

// ---------------- box-average + tiny MLP + 3-way softmax --------------------
__global__ __launch_bounds__(256) void avg_mlp(
    const float* __restrict__ edge, const float* __restrict__ w1, const float* __restrict__ b1,
    const float* __restrict__ w2, const float* __restrict__ b2, float* __restrict__ wts)
{
    const int idx = blockIdx.x * 256 + threadIdx.x;  // 0..65535
    const int b = idx >> 12, rem = idx & 4095, h = rem >> 6, w = rem & 63;
    float s = 0.f;
#pragma unroll
    for (int kh = -1; kh <= 1; kh++) {
        const int hh = h + kh;
        if ((unsigned)hh > 63u) continue;
#pragma unroll
        for (int kw = -1; kw <= 1; kw++) {
            const int ww = w + kw;
            if ((unsigned)ww > 63u) continue;
            s += edge[(size_t)b * 4096 + hh * 64 + ww];
        }
    }
    const float e = s / 9.f;
    float l0 = b2[0], l1 = b2[1], l2 = b2[2];
#pragma unroll
    for (int j = 0; j < 16; j++) {
        float hd = fmaxf(e * w1[j] + b1[j], 0.f);
        l0 += hd * w2[j * 3 + 0];
        l1 += hd * w2[j * 3 + 1];
        l2 += hd * w2[j * 3 + 2];
    }
    const float mx = fmaxf(l0, fmaxf(l1, l2));
    const float e0 = __expf(l0 - mx), e1 = __expf(l1 - mx), e2 = __expf(l2 - mx);
    const float inv = 1.f / (e0 + e1 + e2);
    wts[(size_t)idx * 3 + 0] = e0 * inv;
    wts[(size_t)idx * 3 + 1] = e1 * inv;
    wts[(size_t)idx * 3 + 2] = e2 * inv;
}

// ---------------------- DlightConv token pooling ----------------------------
__global__ __launch_bounds__(256) void dlight(
    const float* __restrict__ S1, const float* __restrict__ dlw,
    const float* __restrict__ dlb, float* __restrict__ XDL)
{
    __shared__ float xw[16][257];
    __shared__ float m[256];
    __shared__ float pr[16];
    __shared__ float pr2[16];
    const int wid = blockIdx.x;  // b*256 + p*16 + q
    const int b = wid >> 8, rem = wid & 255, p = rem >> 4, q = rem & 15;
    const int tid = threadIdx.x;  // channel
#pragma unroll
    for (int t = 0; t < 16; t++) {
        const int ti = t >> 2, tj = t & 3;
        xw[t][tid] = S1[((size_t)b * 4096 + (p * 4 + ti) * 64 + (q * 4 + tj)) * 256 + tid];
    }
    float mm = 0.f;
#pragma unroll
    for (int t = 0; t < 16; t++) mm += xw[t][tid];
    m[tid] = mm * (1.f / 16.f);
    __syncthreads();
    if (tid < 16) {
        float lg = dlb[tid];
        for (int c = 0; c < 256; c++) lg += m[c] * dlw[c * 16 + tid];
        pr[tid] = lg;
    }
    __syncthreads();
    if (tid < 16) {
        float mx = -3.4e38f;
        for (int j = 0; j < 16; j++) mx = fmaxf(mx, pr[j]);
        float sum = 0.f;
        for (int j = 0; j < 16; j++) sum += __expf(pr[j] - mx);
        pr2[tid] = __expf(pr[tid] - mx) / sum;
    }
    __syncthreads();
    float o = 0.f;
#pragma unroll
    for (int t = 0; t < 16; t++) o += xw[t][tid] * pr2[t];
    XDL[(size_t)wid * 256 + tid] = o;
}

// ----------------------------- axial attention ------------------------------
__global__ __launch_bounds__(256) void axial_row(
    const float* __restrict__ Q, const float* __restrict__ K, const float* __restrict__ V,
    const float* __restrict__ gsp, const float* __restrict__ gbp, float* __restrict__ XG)
{
    __shared__ float qs[16][257], ks[16][257], vs[16][257];
    __shared__ float sc[16][17];
    const int bid = blockIdx.x;
    const int b = bid >> 4, r = bid & 15;
    const int tid = threadIdx.x;
    const float gs = gsp[0], gb = gbp[0];
#pragma unroll
    for (int w = 0; w < 16; w++) {
        const size_t base = ((size_t)b * 256 + r * 16 + w) * 256 + tid;
        qs[w][tid] = Q[base]; ks[w][tid] = K[base]; vs[w][tid] = V[base];
    }
    __syncthreads();
    {
        const int w = tid >> 4, vv = tid & 15;
        float s = 0.f;
        for (int c = 0; c < 256; c++) s += qs[w][c] * ks[vv][c];
        const float d = (float)(w - vv);
        sc[w][vv] = s - (gs * d * d + gb);
    }
    __syncthreads();
    if (tid < 16) {
        float mx = -3.4e38f;
        for (int j = 0; j < 16; j++) mx = fmaxf(mx, sc[tid][j]);
        float sum = 0.f;
        for (int j = 0; j < 16; j++) {
            float e = __expf(sc[tid][j] - mx);
            sc[tid][j] = e; sum += e;
        }
        const float inv = 1.f / sum;
        for (int j = 0; j < 16; j++) sc[tid][j] *= inv;
    }
    __syncthreads();
#pragma unroll
    for (int w2 = 0; w2 < 16; w2++) {
        float o = 0.f;
#pragma unroll
        for (int k2 = 0; k2 < 16; k2++) o += sc[w2][k2] * vs[k2][tid];
        XG[((size_t)b * 256 + r * 16 + w2) * 256 + tid] = o;
    }
}

__global__ __launch_bounds__(256) void axial_col(
    const float* __restrict__ Q, const float* __restrict__ K, const float* __restrict__ V,
    const float* __restrict__ gsp, const float* __restrict__ gbp, float* __restrict__ XG)
{
    __shared__ float qs[16][257], ks[16][257], vs[16][257];
    __shared__ float sc[16][17];
    const int bid = blockIdx.x;
    const int b = bid >> 4, col = bid & 15;
    const int tid = threadIdx.x;
    const float gs = gsp[0], gb = gbp[0];
#pragma unroll
    for (int h = 0; h < 16; h++) {
        const size_t base = ((size_t)b * 256 + h * 16 + col) * 256 + tid;
        qs[h][tid] = Q[base]; ks[h][tid] = K[base]; vs[h][tid] = V[base];
    }
    __syncthreads();
    {
        const int r = tid >> 4, vv = tid & 15;
        float s = 0.f;
        for (int c = 0; c < 256; c++) s += qs[r][c] * ks[vv][c];
        const float d = (float)(r - vv);
        sc[r][vv] = s - (gs * d * d + gb);
    }
    __syncthreads();
    if (tid < 16) {
        float mx = -3.4e38f;
        for (int j = 0; j < 16; j++) mx = fmaxf(mx, sc[tid][j]);
        float sum = 0.f;
        for (int j = 0; j < 16; j++) {
            float e = __expf(sc[tid][j] - mx);
            sc[tid][j] = e; sum += e;
        }
        const float inv = 1.f / sum;
        for (int j = 0; j < 16; j++) sc[tid][j] *= inv;
    }
    __syncthreads();
#pragma unroll
    for (int r2 = 0; r2 < 16; r2++) {
        float o = 0.f;
#pragma unroll
        for (int k2 = 0; k2 < 16; k2++) o += sc[r2][k2] * vs[k2][tid];
        XG[((size_t)b * 256 + r2 * 16 + col) * 256 + tid] += o;
    }
}

// -------------------- bilinear upsample 16x16 -> 64x64 ----------------------
// Emits split hi/lo so gemmf's UP half can stage A async.
__global__ __launch_bounds__(256) void upsample(
    const float* __restrict__ XG, ushort* __restrict__ UPH, ushort* __restrict__ UPL)
{
    const unsigned idx = blockIdx.x * 256u + threadIdx.x;
    const int c = idx & 255;
    const unsigned t2 = idx >> 8;
    const int w = t2 & 63;
    const unsigned t3 = t2 >> 6;
    const int h = t3 & 63;
    const int b = t3 >> 6;
    const float rr = 15.f / 63.f;
    const float ph = h * rr, pw = w * rr;
    int h0 = (int)floorf(ph); float th = ph - (float)h0; int h1 = min(h0 + 1, 15);
    int w0 = (int)floorf(pw); float tw = pw - (float)w0; int w1 = min(w0 + 1, 15);
    const size_t bb = (size_t)b * 256;
    const float v00 = XG[((bb + h0 * 16 + w0)) * 256 + c];
    const float v10 = XG[((bb + h1 * 16 + w0)) * 256 + c];
    const float v01 = XG[((bb + h0 * 16 + w1)) * 256 + c];
    const float v11 = XG[((bb + h1 * 16 + w1)) * 256 + c];
    const float c0 = v00 * (1.f - th) + v10 * th;
    const float c1 = v01 * (1.f - th) + v11 * th;
    const float val = c0 * (1.f - tw) + c1 * tw;
    ushort hh, ll; split2(val, hh, ll);
    UPH[idx] = hh; UPL[idx] = ll;
}

// ---------------------------------------------------------------------------
extern "C" void kernel_launch(void* const* d_in, const int* in_sizes, int n_in,
                              void* d_out, int out_size, void* d_ws, size_t ws_size,
                              hipStream_t stream)
{
    const float* x      = (const float*)d_in[0];
    const float* attn_w = (const float*)d_in[1];
    const float* attn_b = (const float*)d_in[2];
    const float* edge_w = (const float*)d_in[3];
    const float* mlp_w1 = (const float*)d_in[4];
    const float* mlp_b1 = (const float*)d_in[5];
    const float* mlp_w2 = (const float*)d_in[6];
    const float* mlp_b2 = (const float*)d_in[7];
    const float* dl_w   = (const float*)d_in[8];
    const float* dl_b   = (const float*)d_in[9];
    const float* ax_w   = (const float*)d_in[10];
    const float* ax_b   = (const float*)d_in[11];
    const float* g_shift= (const float*)d_in[12];
    const float* g_bias = (const float*)d_in[13];
    const float* sq_w   = (const float*)d_in[14];
    const float* sq_b   = (const float*)d_in[15];
    float* out = (float*)d_out;

    float* ws = (float*)d_ws;
    const size_t MT = 65536;
    float* blend = ws;                       // 16,777,216 floats
    float* s1    = blend + MT * 256;         // 16,777,216
    float* scr   = s1 + MT * 256;            // 16,777,216 (ytmp / chunk QKV+ctx / up)
    float* chQ   = scr;
    float* chK   = chQ + (size_t)CHUNK_TOK * 256;
    float* chV   = chK + (size_t)CHUNK_TOK * 256;
    ushort* ctxh = (ushort*)(chV + (size_t)CHUNK_TOK * 256);  // 4,194,304 ushorts
    ushort* ctxl = ctxh + (size_t)CHUNK_TOK * 256;            // 4,194,304 ushorts
    // ctxl ends exactly at scr + MT*256 floats (12.58M + 2*2.10M = 16.77M)
    ushort* uph  = (ushort*)scr;             // 16,777,216 ushorts (chunk bufs dead)
    ushort* upl  = uph + MT * 256;           // 16,777,216 ushorts
    float* ytmp  = scr;                      // 589,824 floats, dead before chQ use
    float* edge  = scr + MT * 256;           // 65,536
    float* wts   = edge + 65536;             // 196,608
    float* xdl   = wts + 196608;             // 1,048,576
    float* axq   = xdl + 1048576;
    float* axk   = axq + 1048576;
    float* axv   = axk + 1048576;
    float* xg    = axv + 1048576;
    ushort* Wth = (ushort*)(xg + 1048576);
    ushort* Wtl = Wth + 1114112;

    // ---- pre-split weights: [n][k] bf16 hi/lo -----------------------------
    split_w_kmajor<<<(12 * 65536 + 255) / 256, 256, 0, stream>>>(attn_w, Wth, Wtl, 12);
    split_w_kmajor<<<(3 * 65536 + 255) / 256, 256, 0, stream>>>(
        ax_w, Wth + (size_t)12 * 65536, Wtl + (size_t)12 * 65536, 3);
    split_w_nmajor<<<(131072 + 255) / 256, 256, 0, stream>>>(
        sq_w, Wth + (size_t)15 * 65536, Wtl + (size_t)15 * 65536, 131072);

    // ---- selector weights (factorized edge conv) --------------------------
    edge_gemm9<<<16384, 256, 0, stream>>>(x, edge_w, ytmp);
    edge_combine<<<256, 256, 0, stream>>>(ytmp, edge);
    avg_mlp<<<256, 256, 0, stream>>>(edge, mlp_w1, mlp_b1, mlp_w2, mlp_b2, wts);

    // ---- three window-attention scales, chunked; blend fused in proj ------
    for (int i = 0; i < 3; i++) {
        const ushort* Wh = Wth + (size_t)i * 4 * 65536;
        const ushort* Wl = Wtl + (size_t)i * 4 * 65536;
        const float* c0 = attn_b + (size_t)(i * 4 + 0) * 256;
        const float* c1 = attn_b + (size_t)(i * 4 + 1) * 256;
        const float* c2 = attn_b + (size_t)(i * 4 + 2) * 256;
        const float* c3 = attn_b + (size_t)(i * 4 + 3) * 256;
        for (int ch = 0; ch < 16 / CHUNK_B; ch++) {
            const size_t toff = (size_t)ch * CHUNK_TOK;
            const float* xc = x + toff * 256;
            gemm3_mfma<<<dim3(CHUNK_TOK / 128, 6), 256, 0, stream>>>(
                xc, Wh, Wl, c0, c1, c2, chQ, chK, chV);
            if (i == 0)
                win_attn<2, 8><<<dim3(CHUNK_B * 32 * 32, 1), 256, 0, stream>>>(chQ, chK, chV, ctxh, ctxl);
            if (i == 1)
                win_attn<4, 4><<<dim3(CHUNK_B * 16 * 16, 2), 256, 0, stream>>>(chQ, chK, chV, ctxh, ctxl);
            if (i == 2)
                win_attn<8, 1><<<dim3(CHUNK_B * 8 * 8, 8), 256, 0, stream>>>(chQ, chK, chV, ctxh, ctxl);
            gemmp_mfma<<<dim3(CHUNK_TOK / 128, 2), 256, 0, stream>>>(
                ctxh, ctxl, Wh + (size_t)3 * 65536, Wl + (size_t)3 * 65536, c3,
                s1, (i == 1) ? 1 : 0, blend, wts, i, (i == 0) ? 1 : 0, (int)toff);
        }
    }

    // ---- DlightConv pooling on s1 -----------------------------------------
    dlight<<<4096, 256, 0, stream>>>(s1, dl_w, dl_b, xdl);

    // ---- axial q,k,v projections (M = 4096) -------------------------------
    gemm3_mfma<<<dim3(4096 / 128, 6), 256, 0, stream>>>(
        xdl, Wth + (size_t)12 * 65536, Wtl + (size_t)12 * 65536,
        ax_b, ax_b + 256, ax_b + 512, axq, axk, axv);
    axial_row<<<256, 256, 0, stream>>>(axq, axk, axv, g_shift, g_bias, xg);
    axial_col<<<256, 256, 0, stream>>>(axq, axk, axv, g_shift, g_bias, xg);

    // ---- upsample 16x16 -> 64x64, pre-split, into reused scr region -------
    upsample<<<65536, 256, 0, stream>>>(xg, uph, upl);

    // ---- final squeeze GEMM (K=512) ---------------------------------------
    gemmf_mfma<<<dim3(512, 2), 256, 0, stream>>>(
        uph, upl, blend, Wth + (size_t)15 * 65536, Wtl + (size_t)15 * 65536, sq_b, out);
}

// Round 3
// 1360.571 us; speedup vs baseline: 1.0191x; 1.0191x over previous
//
#include <hip/hip_runtime.h>
#include <math.h>

// ---------------------------------------------------------------------------
// CSAttention forward, MI355X. GEMMs via split-bf16 (hi/lo) 3-MFMA emulation:
//   A*B ~= Ah*Bh + Al*Bh + Ah*Bl   (fp32 accumulate, ~16 mantissa bits)
// Layout: token maps (b, h*64+w, c) row-major, C=256, B=16.
// R5: edge_conv factorized into edge_gemm9 + edge_combine.
// R6: global_load_lds single-buffer (regressed gemmf: latency exposed/step).
// R7: double-buffered gload_lds (regressed: 64KB LDS -> 2 blocks/CU, 1-deep
//     prefetch can't cover HBM latency; occupancy collapse).
// R8: consolidate to R5's PROVEN 2-barrier register-staged loop + keep only
//     verified-good pieces:
//     - unpadded [128][32] LDS (32 KB total, m97 layout, 5 blocks/CU);
//     - chunk-linear 16B staging (1 dwordx4 + 1 ds_write_b128 per chunk,
//       store start-banks cover all 8 slots -- conflict-free);
//     - pre-split ALL GEMM A-inputs: split_x (x -> hi/lo, stashed in d_out
//       which is dead until gemmf), dlight emits xdl hi/lo, win_attn emits
//       ctx hi/lo, upsample emits UP hi/lo. The split2 VALU chain is gone
//       from every GEMM except gemmf's BLD half. Bit-identical numerics.
// ---------------------------------------------------------------------------

#define CHUNK_B 4
#define CHUNK_TOK (CHUNK_B * 4096)   // 16384 tokens per chunk
#define KS 32                        // LDS k-slice width (elements), 64B rows

typedef __attribute__((ext_vector_type(8))) short short8;
typedef __attribute__((ext_vector_type(8))) unsigned short ushort8;
typedef __attribute__((ext_vector_type(4))) float f32x4;

__device__ __forceinline__ ushort f2bf(float f) {
    union { float f; unsigned u; } v; v.f = f;
    unsigned r = v.u + 0x7fff + ((v.u >> 16) & 1);
    return (ushort)(r >> 16);
}
__device__ __forceinline__ float bf2f(ushort h) {
    union { unsigned u; float f; } v; v.u = ((unsigned)h) << 16; return v.f;
}
__device__ __forceinline__ void split2(float v, ushort& h, ushort& l) {
    h = f2bf(v);
    l = f2bf(v - bf2f(h));
}

// ---------------- weight pre-split kernels ---------------------------------
__global__ __launch_bounds__(256) void split_w_kmajor(
    const float* __restrict__ W, ushort* __restrict__ Th, ushort* __restrict__ Tl, int nmats)
{
    const int idx = blockIdx.x * 256 + threadIdx.x;
    if (idx >= nmats * 65536) return;
    const int mat = idx >> 16, r = idx & 65535;
    const int n = r >> 8, k = r & 255;
    const float v = W[(size_t)mat * 65536 + k * 256 + n];
    ushort h, l; split2(v, h, l);
    Th[idx] = h; Tl[idx] = l;
}
__global__ __launch_bounds__(256) void split_w_nmajor(
    const float* __restrict__ W, ushort* __restrict__ Th, ushort* __restrict__ Tl, int total)
{
    const int idx = blockIdx.x * 256 + threadIdx.x;
    if (idx >= total) return;
    ushort h, l; split2(W[idx], h, l);
    Th[idx] = h; Tl[idx] = l;
}

// ---------------- x pre-split: fp32 -> hi/lo planes (vectorized) ------------
__global__ __launch_bounds__(256) void split_x(
    const float* __restrict__ X, ushort* __restrict__ Xh, ushort* __restrict__ Xl)
{
    const size_t i4 = (size_t)blockIdx.x * 256 + threadIdx.x;  // float4 index
    const float4 v = *(const float4*)(X + i4 * 4);
    ushort4 h, l;
    split2(v.x, h.x, l.x); split2(v.y, h.y, l.y);
    split2(v.z, h.z, l.z); split2(v.w, h.w, l.w);
    *(ushort4*)(Xh + i4 * 4) = h;
    *(ushort4*)(Xl + i4 * 4) = l;
}

// ---------------- MFMA GEMM core pieces (macros for reuse) -----------------
#define GEMM_DECLS                                                            \
    __shared__ ushort Ah[128 * KS], Al[128 * KS], Bh[128 * KS], Bl[128 * KS]; \
    const int tid = threadIdx.x;                                              \
    const int wave = tid >> 6, lane = tid & 63;                               \
    const int quad = lane >> 4, l16 = lane & 15;                              \
    const int wr = (wave >> 1) * 64, wc = (wave & 1) * 64;                    \
    f32x4 acc[4][4];                                                          \
    _Pragma("unroll") for (int i = 0; i < 4; i++)                             \
        _Pragma("unroll") for (int j = 0; j < 4; j++)                         \
            acc[i][j] = (f32x4){0.f, 0.f, 0.f, 0.f};

// Pre-split ushort staging. Thread tid owns 16B chunks (tid, tid+256) of the
// [128][32] buffer: chunk ch -> row ch>>2, kcols (ch&3)*8..+7.
// One dwordx4 global load + one ds_write_b128 per chunk; LDS store start
// bank = (ch*4)%32 -> 8 consecutive lanes cover all 32 banks (conflict-free).
#define STAGE_US(dst, src, strideE, rowbase, k0e)                             \
    _Pragma("unroll") for (int cc = 0; cc < 2; cc++) {                        \
        const int ch = tid + cc * 256;                                        \
        const int r = ch >> 2, kc = (ch & 3) * 8;                             \
        *(ushort8*)&(dst)[ch * 8] =                                           \
            *(const ushort8*)((src) + (size_t)((rowbase) + r) * (strideE) + (k0e) + kc); \
    }

// fp32 A staging (gemmf BLD half only): load float4 x2, split, write 16B.
#define STAGE_F32(AhD, AlD, Aptr, kk)                                         \
    _Pragma("unroll") for (int cc = 0; cc < 2; cc++) {                        \
        const int ch = tid + cc * 256;                                        \
        const int r = ch >> 2, kc = (ch & 3) * 8;                             \
        const float* p = (Aptr) + (size_t)(m0 + r) * 256 + (kk) + kc;         \
        const float4 v0 = *(const float4*)p;                                  \
        const float4 v1 = *(const float4*)(p + 4);                            \
        ushort8 h, l; ushort hh, ll;                                          \
        split2(v0.x, hh, ll); h[0] = hh; l[0] = ll;                           \
        split2(v0.y, hh, ll); h[1] = hh; l[1] = ll;                           \
        split2(v0.z, hh, ll); h[2] = hh; l[2] = ll;                           \
        split2(v0.w, hh, ll); h[3] = hh; l[3] = ll;                           \
        split2(v1.x, hh, ll); h[4] = hh; l[4] = ll;                           \
        split2(v1.y, hh, ll); h[5] = hh; l[5] = ll;                           \
        split2(v1.z, hh, ll); h[6] = hh; l[6] = ll;                           \
        split2(v1.w, hh, ll); h[7] = hh; l[7] = ll;                           \
        *(ushort8*)&(AhD)[ch * 8] = h;                                        \
        *(ushort8*)&(AlD)[ch * 8] = l;                                        \
    }

#define GEMM_COMPUTE                                                          \
    {                                                                         \
        short8 afh[4], afl[4], bfh[4], bfl[4];                                \
        _Pragma("unroll") for (int i = 0; i < 4; i++) {                       \
            const int ro = (wr + i * 16 + l16) * KS + quad * 8;               \
            afh[i] = *(const short8*)&Ah[ro];                                 \
            afl[i] = *(const short8*)&Al[ro];                                 \
        }                                                                     \
        _Pragma("unroll") for (int j = 0; j < 4; j++) {                       \
            const int no = (wc + j * 16 + l16) * KS + quad * 8;               \
            bfh[j] = *(const short8*)&Bh[no];                                 \
            bfl[j] = *(const short8*)&Bl[no];                                 \
        }                                                                     \
        _Pragma("unroll") for (int i = 0; i < 4; i++)                         \
            _Pragma("unroll") for (int j = 0; j < 4; j++) {                   \
                acc[i][j] = __builtin_amdgcn_mfma_f32_16x16x32_bf16(          \
                    afh[i], bfh[j], acc[i][j], 0, 0, 0);                      \
                acc[i][j] = __builtin_amdgcn_mfma_f32_16x16x32_bf16(          \
                    afl[i], bfh[j], acc[i][j], 0, 0, 0);                      \
                acc[i][j] = __builtin_amdgcn_mfma_f32_16x16x32_bf16(          \
                    afh[i], bfl[j], acc[i][j], 0, 0, 0);                      \
            }                                                                 \
    }

// ---------- fused 3-matrix GEMM (Q,K,V or axial q,k,v): grid (M/128, 6) -----
// A pre-split (hi/lo ushort planes) -> pure ushort staging, no split VALU.
__global__ __launch_bounds__(256, 2) void gemm3_mfma(
    const ushort* __restrict__ AgH, const ushort* __restrict__ AgL,
    const ushort* __restrict__ Wth, const ushort* __restrict__ Wtl,
    const float* __restrict__ b0, const float* __restrict__ b1, const float* __restrict__ b2,
    float* __restrict__ O0, float* __restrict__ O1, float* __restrict__ O2)
{
    const int m0 = blockIdx.x * 128;
    const int mat = blockIdx.y >> 1;
    const int col0 = (blockIdx.y & 1) * 128;
    const ushort* wth = Wth + (size_t)mat * 65536 + (size_t)col0 * 256;
    const ushort* wtl = Wtl + (size_t)mat * 65536 + (size_t)col0 * 256;
    GEMM_DECLS
    for (int k0 = 0; k0 < 256; k0 += 32) {
        STAGE_US(Ah, AgH, 256, m0, k0)
        STAGE_US(Al, AgL, 256, m0, k0)
        STAGE_US(Bh, wth, 256, 0, k0)
        STAGE_US(Bl, wtl, 256, 0, k0)
        __syncthreads();
        GEMM_COMPUTE
        __syncthreads();
    }
    const float* bias = (mat == 0) ? b0 : (mat == 1) ? b1 : b2;
    float* O = (mat == 0) ? O0 : (mat == 1) ? O1 : O2;
#pragma unroll
    for (int j = 0; j < 4; j++) {
        const int col = col0 + wc + j * 16 + l16;
        const float bj = bias[col];
#pragma unroll
        for (int i = 0; i < 4; i++) {
            const int rbase = m0 + wr + i * 16 + quad * 4;
#pragma unroll
            for (int r = 0; r < 4; r++)
                O[(size_t)(rbase + r) * 256 + col] = acc[i][j][r] + bj;
        }
    }
}

// ---------- out-projection GEMM with fused blend: grid (M/128, 2) -----------
// A pre-split (ctx hi/lo from win_attn).
__global__ __launch_bounds__(256, 2) void gemmp_mfma(
    const ushort* __restrict__ AgH, const ushort* __restrict__ AgL,
    const ushort* __restrict__ Wth, const ushort* __restrict__ Wtl,
    const float* __restrict__ bias,
    float* __restrict__ Sout, int store_s,
    float* __restrict__ Blnd, const float* __restrict__ wts, int scale_idx, int blend_init,
    int row_off)
{
    const int m0 = blockIdx.x * 128;
    const int col0 = blockIdx.y * 128;
    const ushort* wth = Wth + (size_t)col0 * 256;
    const ushort* wtl = Wtl + (size_t)col0 * 256;
    GEMM_DECLS
    for (int k0 = 0; k0 < 256; k0 += 32) {
        STAGE_US(Ah, AgH, 256, m0, k0)
        STAGE_US(Al, AgL, 256, m0, k0)
        STAGE_US(Bh, wth, 256, 0, k0)
        STAGE_US(Bl, wtl, 256, 0, k0)
        __syncthreads();
        GEMM_COMPUTE
        __syncthreads();
    }
#pragma unroll
    for (int i = 0; i < 4; i++) {
        const int rbase = m0 + wr + i * 16 + quad * 4;
#pragma unroll
        for (int r = 0; r < 4; r++) {
            const size_t grow = (size_t)row_off + rbase + r;
            const float wt = wts[grow * 3 + scale_idx];
#pragma unroll
            for (int j = 0; j < 4; j++) {
                const int col = col0 + wc + j * 16 + l16;
                const float v = acc[i][j][r] + bias[col];
                if (store_s) Sout[grow * 256 + col] = v;
                float* bp = Blnd + grow * 256 + col;
                if (blend_init) *bp = wt * v;
                else            *bp = *bp + wt * v;
            }
        }
    }
}

// ---------- final squeeze: OUT = [UP | BL] @ sq_w^T + sq_b, K=512 -----------
// UP half pre-split; BLD half fp32 register split (blend must stay fp32).
__global__ __launch_bounds__(256, 2) void gemmf_mfma(
    const ushort* __restrict__ UPH, const ushort* __restrict__ UPL,
    const float* __restrict__ BLD,
    const ushort* __restrict__ Wth, const ushort* __restrict__ Wtl,
    const float* __restrict__ SQB, float* __restrict__ OUT)
{
    const int m0 = blockIdx.x * 128;
    const int col0 = blockIdx.y * 128;
    const ushort* wth = Wth + (size_t)col0 * 512;
    const ushort* wtl = Wtl + (size_t)col0 * 512;
    GEMM_DECLS
    for (int k0 = 0; k0 < 512; k0 += 32) {
        if (k0 < 256) {
            STAGE_US(Ah, UPH, 256, m0, k0)
            STAGE_US(Al, UPL, 256, m0, k0)
        } else {
            STAGE_F32(Ah, Al, BLD, (k0 & 255))
        }
        STAGE_US(Bh, wth, 512, 0, k0)
        STAGE_US(Bl, wtl, 512, 0, k0)
        __syncthreads();
        GEMM_COMPUTE
        __syncthreads();
    }
#pragma unroll
    for (int j = 0; j < 4; j++) {
        const int col = col0 + wc + j * 16 + l16;
        const float bj = SQB[col];
#pragma unroll
        for (int i = 0; i < 4; i++) {
            const int rbase = m0 + wr + i * 16 + quad * 4;
#pragma unroll
            for (int r = 0; r < 4; r++)
                OUT[(size_t)(rbase + r) * 256 + col] = acc[i][j][r] + bj;
        }
    }
}

// ----------------- windowed multi-head attention (per window) ---------------
// Emits ctx pre-split (hi/lo) so the out-projection can stage A as ushort.
template <int WS, int NH>
__global__ __launch_bounds__(256) void win_attn(
    const float* __restrict__ Q, const float* __restrict__ K,
    const float* __restrict__ V, ushort* __restrict__ CTXh, ushort* __restrict__ CTXl)
{
    constexpr int WIN = WS * WS;
    constexpr int NW = 64 / WS;
    constexpr int CW = NH * 32;
    __shared__ float qs[WIN][CW + 4], ks[WIN][CW + 4], vs[WIN][CW + 4];
    __shared__ float sc[NH][WIN][WIN + 1];
    const int tid = threadIdx.x;
    const int wid = blockIdx.x;
    const int b = wid / (NW * NW);
    const int rem = wid % (NW * NW);
    const int p = rem / NW, q = rem % NW;
    const int h0 = blockIdx.y * NH;

    for (int idx = tid; idx < WIN * CW; idx += 256) {
        const int i = idx / CW;
        const int cc = idx % CW;
        const int ti = i / WS, tj = i % WS;
        const size_t g = ((size_t)(b * 4096 + (p * WS + ti) * 64 + (q * WS + tj))) * 256 + h0 * 32 + cc;
        qs[i][cc] = Q[g]; ks[i][cc] = K[g]; vs[i][cc] = V[g];
    }
    __syncthreads();
    const float scale = 0.17677669529663687f;  // 1/sqrt(32)
    for (int idx = tid; idx < NH * WIN * WIN; idx += 256) {
        const int hl = idx / (WIN * WIN);
        const int r = idx % (WIN * WIN);
        const int i = r / WIN, j = r % WIN;
        const int co = hl * 32;
        float s = 0.f;
#pragma unroll
        for (int d = 0; d < 32; d++) s += qs[i][co + d] * ks[j][co + d];
        sc[hl][i][j] = s * scale;
    }
    __syncthreads();
    if (tid < NH * WIN) {
        const int hl = tid / WIN, i = tid % WIN;
        float mx = -3.4e38f;
        for (int j = 0; j < WIN; j++) mx = fmaxf(mx, sc[hl][i][j]);
        float sum = 0.f;
        for (int j = 0; j < WIN; j++) {
            float e = __expf(sc[hl][i][j] - mx);
            sc[hl][i][j] = e; sum += e;
        }
        const float inv = 1.f / sum;
        for (int j = 0; j < WIN; j++) sc[hl][i][j] *= inv;
    }
    __syncthreads();
    for (int idx = tid; idx < WIN * CW; idx += 256) {
        const int i = idx / CW;
        const int cc = idx % CW;
        const int hl = cc >> 5;
        float s = 0.f;
        for (int j = 0; j < WIN; j++) s += sc[hl][i][j] * vs[j][cc];
        const int ti = i / WS, tj = i % WS;
        const size_t g = ((size_t)(b * 4096 + (p * WS + ti) * 64 + (q * WS + tj))) * 256 + h0 * 32 + cc;
        ushort hh, ll; split2(s, hh, ll);
        CTXh[g] = hh; CTXl[g] = ll;
    }
}

// -------- edge conv phase 1: y[p][t] = sum_c x[p][c] * ew[c][t] -------------
__global__ __launch_bounds__(256) void edge_gemm9(
    const float* __restrict__ x, const float* __restrict__ ew, float* __restrict__ ytmp)
{
    __shared__ float wsm[2304];   // ew[c*9 + t]
    const int tid = threadIdx.x;
    for (int i = tid; i < 2304; i += 256) wsm[i] = ew[i];
    __syncthreads();
    const int wave = tid >> 6, lane = tid & 63;
    const int p = blockIdx.x * 4 + wave;            // pixel index 0..65535
    const float4 xv = *(const float4*)(x + (size_t)p * 256 + lane * 4);
    float acc[9];
#pragma unroll
    for (int t = 0; t < 9; t++) acc[t] = 0.f;
    const float xs[4] = {xv.x, xv.y, xv.z, xv.w};
#pragma unroll
    for (int i = 0; i < 4; i++) {
        const int c = lane * 4 + i;
#pragma unroll
        for (int t = 0; t < 9; t++)
            acc[t] = fmaf(xs[i], wsm[c * 9 + t], acc[t]);
    }
#pragma unroll
    for (int t = 0; t < 9; t++) {
#pragma unroll
        for (int off = 1; off < 64; off <<= 1)
            acc[t] += __shfl_xor(acc[t], off);
    }
    if (lane < 9) {
        float v = acc[0];
        switch (lane) {
            case 1: v = acc[1]; break; case 2: v = acc[2]; break;
            case 3: v = acc[3]; break; case 4: v = acc[4]; break;
            case 5: v = acc[5]; break; case 6: v = acc[6]; break;
            case 7: v = acc[7]; break; case 8: v = acc[8]; break;
            default: break;
        }
        ytmp[(size_t)p * 9 + lane] = v;
    }
}

// -------- edge conv phase 2: edge[h,w] = |sum_t y[h+dh,w+dw][t]| ------------
__global__ __launch_bounds__(256) void edge_combine(
    const float* __restrict__ ytmp, float* __restrict__ edge)
{
    const int idx = blockIdx.x * 256 + threadIdx.x;   // 0..65535
    const int b = idx >> 12, rem = idx & 4095, h = rem >> 6, w = rem & 63;
    float s = 0.f;
#pragma unroll
    for (int kh = 0; kh < 3; kh++) {
        const int hh = h + kh - 1;
        if ((unsigned)hh > 63u) continue;
#pragma unroll
        for (int kw = 0; kw < 3; kw++) {
            const int ww = w + kw - 1;
            if ((unsigned)ww > 63u) continue;
            s += ytmp[((size_t)b * 4096 + hh * 64 + ww) * 9 + kh * 3 + kw];
        }
    }
    edge[idx] = fabsf(s);
}

// ---------------- box-average + tiny MLP + 3-way softmax --------------------
__global__ __launch_bounds__(256) void avg_mlp(
    const float* __restrict__ edge, const float* __restrict__ w1, const float* __restrict__ b1,
    const float* __restrict__ w2, const float* __restrict__ b2, float* __restrict__ wts)
{
    const int idx = blockIdx.x * 256 + threadIdx.x;  // 0..65535
    const int b = idx >> 12, rem = idx & 4095, h = rem >> 6, w = rem & 63;
    float s = 0.f;
#pragma unroll
    for (int kh = -1; kh <= 1; kh++) {
        const int hh = h + kh;
        if ((unsigned)hh > 63u) continue;
#pragma unroll
        for (int kw = -1; kw <= 1; kw++) {
            const int ww = w + kw;
            if ((unsigned)ww > 63u) continue;
            s += edge[(size_t)b * 4096 + hh * 64 + ww];
        }
    }
    const float e = s / 9.f;
    float l0 = b2[0], l1 = b2[1], l2 = b2[2];
#pragma unroll
    for (int j = 0; j < 16; j++) {
        float hd = fmaxf(e * w1[j] + b1[j], 0.f);
        l0 += hd * w2[j * 3 + 0];
        l1 += hd * w2[j * 3 + 1];
        l2 += hd * w2[j * 3 + 2];
    }
    const float mx = fmaxf(l0, fmaxf(l1, l2));
    const float e0 = __expf(l0 - mx), e1 = __expf(l1 - mx), e2 = __expf(l2 - mx);
    const float inv = 1.f / (e0 + e1 + e2);
    wts[(size_t)idx * 3 + 0] = e0 * inv;
    wts[(size_t)idx * 3 + 1] = e1 * inv;
    wts[(size_t)idx * 3 + 2] = e2 * inv;
}

// ---------------------- DlightConv token pooling ----------------------------
// Emits xdl pre-split (hi/lo) for the axial gemm3.
__global__ __launch_bounds__(256) void dlight(
    const float* __restrict__ S1, const float* __restrict__ dlw,
    const float* __restrict__ dlb, ushort* __restrict__ XDLH, ushort* __restrict__ XDLL)
{
    __shared__ float xw[16][257];
    __shared__ float m[256];
    __shared__ float pr[16];
    __shared__ float pr2[16];
    const int wid = blockIdx.x;  // b*256 + p*16 + q
    const int b = wid >> 8, rem = wid & 255, p = rem >> 4, q = rem & 15;
    const int tid = threadIdx.x;  // channel
#pragma unroll
    for (int t = 0; t < 16; t++) {
        const int ti = t >> 2, tj = t & 3;
        xw[t][tid] = S1[((size_t)b * 4096 + (p * 4 + ti) * 64 + (q * 4 + tj)) * 256 + tid];
    }
    float mm = 0.f;
#pragma unroll
    for (int t = 0; t < 16; t++) mm += xw[t][tid];
    m[tid] = mm * (1.f / 16.f);
    __syncthreads();
    if (tid < 16) {
        float lg = dlb[tid];
        for (int c = 0; c < 256; c++) lg += m[c] * dlw[c * 16 + tid];
        pr[tid] = lg;
    }
    __syncthreads();
    if (tid < 16) {
        float mx = -3.4e38f;
        for (int j = 0; j < 16; j++) mx = fmaxf(mx, pr[j]);
        float sum = 0.f;
        for (int j = 0; j < 16; j++) sum += __expf(pr[j] - mx);
        pr2[tid] = __expf(pr[tid] - mx) / sum;
    }
    __syncthreads();
    float o = 0.f;
#pragma unroll
    for (int t = 0; t < 16; t++) o += xw[t][tid] * pr2[t];
    ushort hh, ll; split2(o, hh, ll);
    XDLH[(size_t)wid * 256 + tid] = hh;
    XDLL[(size_t)wid * 256 + tid] = ll;
}

// ----------------------------- axial attention ------------------------------
__global__ __launch_bounds__(256) void axial_row(
    const float* __restrict__ Q, const float* __restrict__ K, const float* __restrict__ V,
    const float* __restrict__ gsp, const float* __restrict__ gbp, float* __restrict__ XG)
{
    __shared__ float qs[16][257], ks[16][257], vs[16][257];
    __shared__ float sc[16][17];
    const int bid = blockIdx.x;
    const int b = bid >> 4, r = bid & 15;
    const int tid = threadIdx.x;
    const float gs = gsp[0], gb = gbp[0];
#pragma unroll
    for (int w = 0; w < 16; w++) {
        const size_t base = ((size_t)b * 256 + r * 16 + w) * 256 + tid;
        qs[w][tid] = Q[base]; ks[w][tid] = K[base]; vs[w][tid] = V[base];
    }
    __syncthreads();
    {
        const int w = tid >> 4, vv = tid & 15;
        float s = 0.f;
        for (int c = 0; c < 256; c++) s += qs[w][c] * ks[vv][c];
        const float d = (float)(w - vv);
        sc[w][vv] = s - (gs * d * d + gb);
    }
    __syncthreads();
    if (tid < 16) {
        float mx = -3.4e38f;
        for (int j = 0; j < 16; j++) mx = fmaxf(mx, sc[tid][j]);
        float sum = 0.f;
        for (int j = 0; j < 16; j++) {
            float e = __expf(sc[tid][j] - mx);
            sc[tid][j] = e; sum += e;
        }
        const float inv = 1.f / sum;
        for (int j = 0; j < 16; j++) sc[tid][j] *= inv;
    }
    __syncthreads();
#pragma unroll
    for (int w2 = 0; w2 < 16; w2++) {
        float o = 0.f;
#pragma unroll
        for (int k2 = 0; k2 < 16; k2++) o += sc[w2][k2] * vs[k2][tid];
        XG[((size_t)b * 256 + r * 16 + w2) * 256 + tid] = o;
    }
}

__global__ __launch_bounds__(256) void axial_col(
    const float* __restrict__ Q, const float* __restrict__ K, const float* __restrict__ V,
    const float* __restrict__ gsp, const float* __restrict__ gbp, float* __restrict__ XG)
{
    __shared__ float qs[16][257], ks[16][257], vs[16][257];
    __shared__ float sc[16][17];
    const int bid = blockIdx.x;
    const int b = bid >> 4, col = bid & 15;
    const int tid = threadIdx.x;
    const float gs = gsp[0], gb = gbp[0];
#pragma unroll
    for (int h = 0; h < 16; h++) {
        const size_t base = ((size_t)b * 256 + h * 16 + col) * 256 + tid;
        qs[h][tid] = Q[base]; ks[h][tid] = K[base]; vs[h][tid] = V[base];
    }
    __syncthreads();
    {
        const int r = tid >> 4, vv = tid & 15;
        float s = 0.f;
        for (int c = 0; c < 256; c++) s += qs[r][c] * ks[vv][c];
        const float d = (float)(r - vv);
        sc[r][vv] = s - (gs * d * d + gb);
    }
    __syncthreads();
    if (tid < 16) {
        float mx = -3.4e38f;
        for (int j = 0; j < 16; j++) mx = fmaxf(mx, sc[tid][j]);
        float sum = 0.f;
        for (int j = 0; j < 16; j++) {
            float e = __expf(sc[tid][j] - mx);
            sc[tid][j] = e; sum += e;
        }
        const float inv = 1.f / sum;
        for (int j = 0; j < 16; j++) sc[tid][j] *= inv;
    }
    __syncthreads();
#pragma unroll
    for (int r2 = 0; r2 < 16; r2++) {
        float o = 0.f;
#pragma unroll
        for (int k2 = 0; k2 < 16; k2++) o += sc[r2][k2] * vs[k2][tid];
        XG[((size_t)b * 256 + r2 * 16 + col) * 256 + tid] += o;
    }
}

// -------------------- bilinear upsample 16x16 -> 64x64 ----------------------
// Emits split hi/lo so gemmf's UP half stages A as ushort.
__global__ __launch_bounds__(256) void upsample(
    const float* __restrict__ XG, ushort* __restrict__ UPH, ushort* __restrict__ UPL)
{
    const unsigned idx = blockIdx.x * 256u + threadIdx.x;
    const int c = idx & 255;
    const unsigned t2 = idx >> 8;
    const int w = t2 & 63;
    const unsigned t3 = t2 >> 6;
    const int h = t3 & 63;
    const int b = t3 >> 6;
    const float rr = 15.f / 63.f;
    const float ph = h * rr, pw = w * rr;
    int h0 = (int)floorf(ph); float th = ph - (float)h0; int h1 = min(h0 + 1, 15);
    int w0 = (int)floorf(pw); float tw = pw - (float)w0; int w1 = min(w0 + 1, 15);
    const size_t bb = (size_t)b * 256;
    const float v00 = XG[((bb + h0 * 16 + w0)) * 256 + c];
    const float v10 = XG[((bb + h1 * 16 + w0)) * 256 + c];
    const float v01 = XG[((bb + h0 * 16 + w1)) * 256 + c];
    const float v11 = XG[((bb + h1 * 16 + w1)) * 256 + c];
    const float c0 = v00 * (1.f - th) + v10 * th;
    const float c1 = v01 * (1.f - th) + v11 * th;
    const float val = c0 * (1.f - tw) + c1 * tw;
    ushort hh, ll; split2(val, hh, ll);
    UPH[idx] = hh; UPL[idx] = ll;
}

// ---------------------------------------------------------------------------
extern "C" void kernel_launch(void* const* d_in, const int* in_sizes, int n_in,
                              void* d_out, int out_size, void* d_ws, size_t ws_size,
                              hipStream_t stream)
{
    const float* x      = (const float*)d_in[0];
    const float* attn_w = (const float*)d_in[1];
    const float* attn_b = (const float*)d_in[2];
    const float* edge_w = (const float*)d_in[3];
    const float* mlp_w1 = (const float*)d_in[4];
    const float* mlp_b1 = (const float*)d_in[5];
    const float* mlp_w2 = (const float*)d_in[6];
    const float* mlp_b2 = (const float*)d_in[7];
    const float* dl_w   = (const float*)d_in[8];
    const float* dl_b   = (const float*)d_in[9];
    const float* ax_w   = (const float*)d_in[10];
    const float* ax_b   = (const float*)d_in[11];
    const float* g_shift= (const float*)d_in[12];
    const float* g_bias = (const float*)d_in[13];
    const float* sq_w   = (const float*)d_in[14];
    const float* sq_b   = (const float*)d_in[15];
    float* out = (float*)d_out;

    float* ws = (float*)d_ws;
    const size_t MT = 65536;
    float* blend = ws;                       // 16,777,216 floats
    float* s1    = blend + MT * 256;         // 16,777,216
    float* scr   = s1 + MT * 256;            // 16,777,216 (ytmp / chunk QKV+ctx / up)
    float* chQ   = scr;
    float* chK   = chQ + (size_t)CHUNK_TOK * 256;
    float* chV   = chK + (size_t)CHUNK_TOK * 256;
    ushort* ctxh = (ushort*)(chV + (size_t)CHUNK_TOK * 256);  // 4,194,304 ushorts
    ushort* ctxl = ctxh + (size_t)CHUNK_TOK * 256;            // 4,194,304 ushorts
    // ctxl ends exactly at scr + MT*256 floats (12.58M + 2*2.10M = 16.77M)
    ushort* uph  = (ushort*)scr;             // 16,777,216 ushorts (chunk bufs dead)
    ushort* upl  = uph + MT * 256;           // 16,777,216 ushorts
    float* ytmp  = scr;                      // 589,824 floats, dead before chQ use
    float* edge  = scr + MT * 256;           // 65,536
    float* wts   = edge + 65536;             // 196,608
    float* xdl   = wts + 196608;             // 1,048,576 floats region
    ushort* xdlh = (ushort*)xdl;             // 1,048,576 ushorts (2 MB)
    ushort* xdll = xdlh + 1048576;           // 1,048,576 ushorts (2 MB)
    float* axq   = xdl + 1048576;
    float* axk   = axq + 1048576;
    float* axv   = axk + 1048576;
    float* xg    = axv + 1048576;
    ushort* Wth = (ushort*)(xg + 1048576);
    ushort* Wtl = Wth + 1114112;
    // x hi/lo planes live in d_out (dead until gemmf writes it at the end)
    ushort* xh = (ushort*)out;               // 16,777,216 ushorts (32 MB)
    ushort* xl = xh + MT * 256;              // 16,777,216 ushorts (32 MB)

    // ---- pre-split weights: [n][k] bf16 hi/lo -----------------------------
    split_w_kmajor<<<(12 * 65536 + 255) / 256, 256, 0, stream>>>(attn_w, Wth, Wtl, 12);
    split_w_kmajor<<<(3 * 65536 + 255) / 256, 256, 0, stream>>>(
        ax_w, Wth + (size_t)12 * 65536, Wtl + (size_t)12 * 65536, 3);
    split_w_nmajor<<<(131072 + 255) / 256, 256, 0, stream>>>(
        sq_w, Wth + (size_t)15 * 65536, Wtl + (size_t)15 * 65536, 131072);

    // ---- pre-split x once (used by all 12 window gemm3 launches) ----------
    split_x<<<16384, 256, 0, stream>>>(x, xh, xl);

    // ---- selector weights (factorized edge conv) --------------------------
    edge_gemm9<<<16384, 256, 0, stream>>>(x, edge_w, ytmp);
    edge_combine<<<256, 256, 0, stream>>>(ytmp, edge);
    avg_mlp<<<256, 256, 0, stream>>>(edge, mlp_w1, mlp_b1, mlp_w2, mlp_b2, wts);

    // ---- three window-attention scales, chunked; blend fused in proj ------
    for (int i = 0; i < 3; i++) {
        const ushort* Wh = Wth + (size_t)i * 4 * 65536;
        const ushort* Wl = Wtl + (size_t)i * 4 * 65536;
        const float* c0 = attn_b + (size_t)(i * 4 + 0) * 256;
        const float* c1 = attn_b + (size_t)(i * 4 + 1) * 256;
        const float* c2 = attn_b + (size_t)(i * 4 + 2) * 256;
        const float* c3 = attn_b + (size_t)(i * 4 + 3) * 256;
        for (int ch = 0; ch < 16 / CHUNK_B; ch++) {
            const size_t toff = (size_t)ch * CHUNK_TOK;
            gemm3_mfma<<<dim3(CHUNK_TOK / 128, 6), 256, 0, stream>>>(
                xh + toff * 256, xl + toff * 256, Wh, Wl, c0, c1, c2, chQ, chK, chV);
            if (i == 0)
                win_attn<2, 8><<<dim3(CHUNK_B * 32 * 32, 1), 256, 0, stream>>>(chQ, chK, chV, ctxh, ctxl);
            if (i == 1)
                win_attn<4, 4><<<dim3(CHUNK_B * 16 * 16, 2), 256, 0, stream>>>(chQ, chK, chV, ctxh, ctxl);
            if (i == 2)
                win_attn<8, 1><<<dim3(CHUNK_B * 8 * 8, 8), 256, 0, stream>>>(chQ, chK, chV, ctxh, ctxl);
            gemmp_mfma<<<dim3(CHUNK_TOK / 128, 2), 256, 0, stream>>>(
                ctxh, ctxl, Wh + (size_t)3 * 65536, Wl + (size_t)3 * 65536, c3,
                s1, (i == 1) ? 1 : 0, blend, wts, i, (i == 0) ? 1 : 0, (int)toff);
        }
    }

    // ---- DlightConv pooling on s1 (emits pre-split xdl) -------------------
    dlight<<<4096, 256, 0, stream>>>(s1, dl_w, dl_b, xdlh, xdll);

    // ---- axial q,k,v projections (M = 4096) -------------------------------
    gemm3_mfma<<<dim3(4096 / 128, 6), 256, 0, stream>>>(
        xdlh, xdll, Wth + (size_t)12 * 65536, Wtl + (size_t)12 * 65536,
        ax_b, ax_b + 256, ax_b + 512, axq, axk, axv);
    axial_row<<<256, 256, 0, stream>>>(axq, axk, axv, g_shift, g_bias, xg);
    axial_col<<<256, 256, 0, stream>>>(axq, axk, axv, g_shift, g_bias, xg);

    // ---- upsample 16x16 -> 64x64, pre-split, into reused scr region -------
    upsample<<<65536, 256, 0, stream>>>(xg, uph, upl);

    // ---- final squeeze GEMM (K=512) ---------------------------------------
    gemmf_mfma<<<dim3(512, 2), 256, 0, stream>>>(
        uph, upl, blend, Wth + (size_t)15 * 65536, Wtl + (size_t)15 * 65536, sq_b, out);
}

// Round 4
// 1300.388 us; speedup vs baseline: 1.0663x; 1.0463x over previous
//
#include <hip/hip_runtime.h>
#include <math.h>

// ---------------------------------------------------------------------------
// CSAttention forward, MI355X. GEMMs via split-bf16 (hi/lo) 3-MFMA emulation:
//   A*B ~= Ah*Bh + Al*Bh + Ah*Bl   (fp32 accumulate, ~16 mantissa bits)
// Layout: token maps (b, h*64+w, c) row-major, C=256, B=16.
// R5: edge_conv factorized into edge_gemm9 + edge_combine.
// R6: gload_lds single-buffer everywhere (total-best 1295.8; unpadded reads
//     were the hidden 2x LDS serialization).
// R7: dbuf gload (occupancy collapse).  R8: reg chunk staging (worst).
// R9: bothsides XOR swizzle on the linear [128][32] LDS (rule #21):
//     - global SOURCE pre-swizzled per lane (kchunk ^= (row>>1)&3, involution
//       within a row's four 16B chunks) so gload_lds's linear dest lands data
//       swizzled; reads XOR the same pattern (quad*8 ^ ((l16>>1)&3)*8).
//     - read/write bank-starts now cover all 8 four-bank groups within every
//       16-lane quad -> conflict-free b128 both directions, 32 KB LDS kept.
//     - x pre-split fused into edge_gemm9 (no separate split_x kernel);
//       all GEMM A-operands pre-split (ctx/xdl/UP from producers).
//     - only gemmf's BLD half stays fp32 reg-staged (swizzled ds_write_b128).
// ---------------------------------------------------------------------------

#define CHUNK_B 4
#define CHUNK_TOK (CHUNK_B * 4096)   // 16384 tokens per chunk
#define KS 32                        // LDS k-slice width (elements), 64B rows

typedef __attribute__((ext_vector_type(8))) short short8;
typedef __attribute__((ext_vector_type(8))) unsigned short ushort8;
typedef __attribute__((ext_vector_type(4))) float f32x4;

__device__ __forceinline__ ushort f2bf(float f) {
    union { float f; unsigned u; } v; v.f = f;
    unsigned r = v.u + 0x7fff + ((v.u >> 16) & 1);
    return (ushort)(r >> 16);
}
__device__ __forceinline__ float bf2f(ushort h) {
    union { unsigned u; float f; } v; v.u = ((unsigned)h) << 16; return v.f;
}
__device__ __forceinline__ void split2(float v, ushort& h, ushort& l) {
    h = f2bf(v);
    l = f2bf(v - bf2f(h));
}

// async 16B/lane global -> LDS (wave-uniform LDS base, per-lane global addr)
__device__ __forceinline__ void gld16(const ushort* g, ushort* l) {
    __builtin_amdgcn_global_load_lds(
        (const __attribute__((address_space(1))) unsigned int*)g,
        (__attribute__((address_space(3))) unsigned int*)l,
        16, 0, 0);
}

// ---------------- weight pre-split kernels ---------------------------------
__global__ __launch_bounds__(256) void split_w_kmajor(
    const float* __restrict__ W, ushort* __restrict__ Th, ushort* __restrict__ Tl, int nmats)
{
    const int idx = blockIdx.x * 256 + threadIdx.x;
    if (idx >= nmats * 65536) return;
    const int mat = idx >> 16, r = idx & 65535;
    const int n = r >> 8, k = r & 255;
    const float v = W[(size_t)mat * 65536 + k * 256 + n];
    ushort h, l; split2(v, h, l);
    Th[idx] = h; Tl[idx] = l;
}
__global__ __launch_bounds__(256) void split_w_nmajor(
    const float* __restrict__ W, ushort* __restrict__ Th, ushort* __restrict__ Tl, int total)
{
    const int idx = blockIdx.x * 256 + threadIdx.x;
    if (idx >= total) return;
    ushort h, l; split2(W[idx], h, l);
    Th[idx] = h; Tl[idx] = l;
}

// ---------------- MFMA GEMM core pieces (macros for reuse) -----------------
#define GEMM_DECLS                                                            \
    __shared__ ushort Ah[128 * KS], Al[128 * KS], Bh[128 * KS], Bl[128 * KS]; \
    const int tid = threadIdx.x;                                              \
    const int wave = tid >> 6, lane = tid & 63;                               \
    const int quad = lane >> 4, l16 = lane & 15;                              \
    const int wr = (wave >> 1) * 64, wc = (wave & 1) * 64;                    \
    f32x4 acc[4][4];                                                          \
    _Pragma("unroll") for (int i = 0; i < 4; i++)                             \
        _Pragma("unroll") for (int j = 0; j < 4; j++)                         \
            acc[i][j] = (f32x4){0.f, 0.f, 0.f, 0.f};

// Async stage one 128xKS ushort buffer. LDS dest is LINEAR (lane*16B); the
// per-lane GLOBAL k-chunk is pre-swizzled (kq ^= (row>>1)&3, an involution)
// so data lands in the swizzled layout that the compute reads expect.
#define STAGE_GLD(dstbuf, srcp, strideE, rowbase, k0e)                        \
    _Pragma("unroll") for (int jj = 0; jj < 2; jj++) {                        \
        const int rr = (wave << 5) + (jj << 4) + (lane >> 2);                 \
        const int kqs = (lane & 3) ^ ((lane >> 3) & 3);                       \
        gld16((srcp) + (size_t)((rowbase) + rr) * (strideE) + (k0e) + (kqs << 3), \
              (dstbuf) + (wave << 10) + (jj << 9));                           \
    }

// fp32 A staging (gemmf BLD half only): load float4 x2, split, write 16B to
// the swizzled slot (dest-side swizzle; source stays linear for reg staging).
#define STAGE_F32(AhD, AlD, Aptr, kk)                                         \
    _Pragma("unroll") for (int cc = 0; cc < 2; cc++) {                        \
        const int ch = tid + cc * 256;                                        \
        const int r = ch >> 2, kq = ch & 3;                                   \
        const int wsl = (kq ^ ((r >> 1) & 3)) * 8;                            \
        const float* p = (Aptr) + (size_t)(m0 + r) * 256 + (kk) + kq * 8;     \
        const float4 v0 = *(const float4*)p;                                  \
        const float4 v1 = *(const float4*)(p + 4);                            \
        ushort8 h, l; ushort hh, ll;                                          \
        split2(v0.x, hh, ll); h[0] = hh; l[0] = ll;                           \
        split2(v0.y, hh, ll); h[1] = hh; l[1] = ll;                           \
        split2(v0.z, hh, ll); h[2] = hh; l[2] = ll;                           \
        split2(v0.w, hh, ll); h[3] = hh; l[3] = ll;                           \
        split2(v1.x, hh, ll); h[4] = hh; l[4] = ll;                           \
        split2(v1.y, hh, ll); h[5] = hh; l[5] = ll;                           \
        split2(v1.z, hh, ll); h[6] = hh; l[6] = ll;                           \
        split2(v1.w, hh, ll); h[7] = hh; l[7] = ll;                           \
        *(ushort8*)&(AhD)[r * KS + wsl] = h;                                  \
        *(ushort8*)&(AlD)[r * KS + wsl] = l;                                  \
    }

// Fragment reads XOR the same swizzle: slot = quad ^ ((l16>>1)&3).
#define GEMM_COMPUTE                                                          \
    {                                                                         \
        const int aswz = (l16 & 6) << 2;  /* ((l16>>1)&3)*8 */                \
        short8 afh[4], afl[4], bfh[4], bfl[4];                                \
        _Pragma("unroll") for (int i = 0; i < 4; i++) {                       \
            const int ro = (wr + i * 16 + l16) * KS + ((quad * 8) ^ aswz);    \
            afh[i] = *(const short8*)&Ah[ro];                                 \
            afl[i] = *(const short8*)&Al[ro];                                 \
        }                                                                     \
        _Pragma("unroll") for (int j = 0; j < 4; j++) {                       \
            const int no = (wc + j * 16 + l16) * KS + ((quad * 8) ^ aswz);    \
            bfh[j] = *(const short8*)&Bh[no];                                 \
            bfl[j] = *(const short8*)&Bl[no];                                 \
        }                                                                     \
        _Pragma("unroll") for (int i = 0; i < 4; i++)                         \
            _Pragma("unroll") for (int j = 0; j < 4; j++) {                   \
                acc[i][j] = __builtin_amdgcn_mfma_f32_16x16x32_bf16(          \
                    afh[i], bfh[j], acc[i][j], 0, 0, 0);                      \
                acc[i][j] = __builtin_amdgcn_mfma_f32_16x16x32_bf16(          \
                    afl[i], bfh[j], acc[i][j], 0, 0, 0);                      \
                acc[i][j] = __builtin_amdgcn_mfma_f32_16x16x32_bf16(          \
                    afh[i], bfl[j], acc[i][j], 0, 0, 0);                      \
            }                                                                 \
    }

// ---------- fused 3-matrix GEMM (Q,K,V or axial q,k,v): grid (M/128, 6) -----
// A pre-split (hi/lo ushort planes) -> all four buffers async gload_lds.
__global__ __launch_bounds__(256, 2) void gemm3_mfma(
    const ushort* __restrict__ AgH, const ushort* __restrict__ AgL,
    const ushort* __restrict__ Wth, const ushort* __restrict__ Wtl,
    const float* __restrict__ b0, const float* __restrict__ b1, const float* __restrict__ b2,
    float* __restrict__ O0, float* __restrict__ O1, float* __restrict__ O2)
{
    const int m0 = blockIdx.x * 128;
    const int mat = blockIdx.y >> 1;
    const int col0 = (blockIdx.y & 1) * 128;
    const ushort* wth = Wth + (size_t)mat * 65536 + (size_t)col0 * 256;
    const ushort* wtl = Wtl + (size_t)mat * 65536 + (size_t)col0 * 256;
    GEMM_DECLS
    for (int k0 = 0; k0 < 256; k0 += 32) {
        STAGE_GLD(Ah, AgH, 256, m0, k0)
        STAGE_GLD(Al, AgL, 256, m0, k0)
        STAGE_GLD(Bh, wth, 256, 0, k0)
        STAGE_GLD(Bl, wtl, 256, 0, k0)
        __syncthreads();
        GEMM_COMPUTE
        __syncthreads();
    }
    const float* bias = (mat == 0) ? b0 : (mat == 1) ? b1 : b2;
    float* O = (mat == 0) ? O0 : (mat == 1) ? O1 : O2;
#pragma unroll
    for (int j = 0; j < 4; j++) {
        const int col = col0 + wc + j * 16 + l16;
        const float bj = bias[col];
#pragma unroll
        for (int i = 0; i < 4; i++) {
            const int rbase = m0 + wr + i * 16 + quad * 4;
#pragma unroll
            for (int r = 0; r < 4; r++)
                O[(size_t)(rbase + r) * 256 + col] = acc[i][j][r] + bj;
        }
    }
}

// ---------- out-projection GEMM with fused blend: grid (M/128, 2) -----------
// A pre-split (ctx hi/lo from win_attn) -> fully async staging.
__global__ __launch_bounds__(256, 2) void gemmp_mfma(
    const ushort* __restrict__ AgH, const ushort* __restrict__ AgL,
    const ushort* __restrict__ Wth, const ushort* __restrict__ Wtl,
    const float* __restrict__ bias,
    float* __restrict__ Sout, int store_s,
    float* __restrict__ Blnd, const float* __restrict__ wts, int scale_idx, int blend_init,
    int row_off)
{
    const int m0 = blockIdx.x * 128;
    const int col0 = blockIdx.y * 128;
    const ushort* wth = Wth + (size_t)col0 * 256;
    const ushort* wtl = Wtl + (size_t)col0 * 256;
    GEMM_DECLS
    for (int k0 = 0; k0 < 256; k0 += 32) {
        STAGE_GLD(Ah, AgH, 256, m0, k0)
        STAGE_GLD(Al, AgL, 256, m0, k0)
        STAGE_GLD(Bh, wth, 256, 0, k0)
        STAGE_GLD(Bl, wtl, 256, 0, k0)
        __syncthreads();
        GEMM_COMPUTE
        __syncthreads();
    }
#pragma unroll
    for (int i = 0; i < 4; i++) {
        const int rbase = m0 + wr + i * 16 + quad * 4;
#pragma unroll
        for (int r = 0; r < 4; r++) {
            const size_t grow = (size_t)row_off + rbase + r;
            const float wt = wts[grow * 3 + scale_idx];
#pragma unroll
            for (int j = 0; j < 4; j++) {
                const int col = col0 + wc + j * 16 + l16;
                const float v = acc[i][j][r] + bias[col];
                if (store_s) Sout[grow * 256 + col] = v;
                float* bp = Blnd + grow * 256 + col;
                if (blend_init) *bp = wt * v;
                else            *bp = *bp + wt * v;
            }
        }
    }
}

// ---------- final squeeze: OUT = [UP | BL] @ sq_w^T + sq_b, K=512 -----------
// UP half pre-split -> async; BLD half fp32 reg split, swizzled ds_write.
__global__ __launch_bounds__(256, 2) void gemmf_mfma(
    const ushort* __restrict__ UPH, const ushort* __restrict__ UPL,
    const float* __restrict__ BLD,
    const ushort* __restrict__ Wth, const ushort* __restrict__ Wtl,
    const float* __restrict__ SQB, float* __restrict__ OUT)
{
    const int m0 = blockIdx.x * 128;
    const int col0 = blockIdx.y * 128;
    const ushort* wth = Wth + (size_t)col0 * 512;
    const ushort* wtl = Wtl + (size_t)col0 * 512;
    GEMM_DECLS
    for (int k0 = 0; k0 < 512; k0 += 32) {
        if (k0 < 256) {
            STAGE_GLD(Ah, UPH, 256, m0, k0)
            STAGE_GLD(Al, UPL, 256, m0, k0)
        } else {
            STAGE_F32(Ah, Al, BLD, (k0 & 255))
        }
        STAGE_GLD(Bh, wth, 512, 0, k0)
        STAGE_GLD(Bl, wtl, 512, 0, k0)
        __syncthreads();
        GEMM_COMPUTE
        __syncthreads();
    }
#pragma unroll
    for (int j = 0; j < 4; j++) {
        const int col = col0 + wc + j * 16 + l16;
        const float bj = SQB[col];
#pragma unroll
        for (int i = 0; i < 4; i++) {
            const int rbase = m0 + wr + i * 16 + quad * 4;
#pragma unroll
            for (int r = 0; r < 4; r++)
                OUT[(size_t)(rbase + r) * 256 + col] = acc[i][j][r] + bj;
        }
    }
}

// ----------------- windowed multi-head attention (per window) ---------------
// Emits ctx pre-split (hi/lo) so the out-projection can stage A async.
template <int WS, int NH>
__global__ __launch_bounds__(256) void win_attn(
    const float* __restrict__ Q, const float* __restrict__ K,
    const float* __restrict__ V, ushort* __restrict__ CTXh, ushort* __restrict__ CTXl)
{
    constexpr int WIN = WS * WS;
    constexpr int NW = 64 / WS;
    constexpr int CW = NH * 32;
    __shared__ float qs[WIN][CW + 4], ks[WIN][CW + 4], vs[WIN][CW + 4];
    __shared__ float sc[NH][WIN][WIN + 1];
    const int tid = threadIdx.x;
    const int wid = blockIdx.x;
    const int b = wid / (NW * NW);
    const int rem = wid % (NW * NW);
    const int p = rem / NW, q = rem % NW;
    const int h0 = blockIdx.y * NH;

    for (int idx = tid; idx < WIN * CW; idx += 256) {
        const int i = idx / CW;
        const int cc = idx % CW;
        const int ti = i / WS, tj = i % WS;
        const size_t g = ((size_t)(b * 4096 + (p * WS + ti) * 64 + (q * WS + tj))) * 256 + h0 * 32 + cc;
        qs[i][cc] = Q[g]; ks[i][cc] = K[g]; vs[i][cc] = V[g];
    }
    __syncthreads();
    const float scale = 0.17677669529663687f;  // 1/sqrt(32)
    for (int idx = tid; idx < NH * WIN * WIN; idx += 256) {
        const int hl = idx / (WIN * WIN);
        const int r = idx % (WIN * WIN);
        const int i = r / WIN, j = r % WIN;
        const int co = hl * 32;
        float s = 0.f;
#pragma unroll
        for (int d = 0; d < 32; d++) s += qs[i][co + d] * ks[j][co + d];
        sc[hl][i][j] = s * scale;
    }
    __syncthreads();
    if (tid < NH * WIN) {
        const int hl = tid / WIN, i = tid % WIN;
        float mx = -3.4e38f;
        for (int j = 0; j < WIN; j++) mx = fmaxf(mx, sc[hl][i][j]);
        float sum = 0.f;
        for (int j = 0; j < WIN; j++) {
            float e = __expf(sc[hl][i][j] - mx);
            sc[hl][i][j] = e; sum += e;
        }
        const float inv = 1.f / sum;
        for (int j = 0; j < WIN; j++) sc[hl][i][j] *= inv;
    }
    __syncthreads();
    for (int idx = tid; idx < WIN * CW; idx += 256) {
        const int i = idx / CW;
        const int cc = idx % CW;
        const int hl = cc >> 5;
        float s = 0.f;
        for (int j = 0; j < WIN; j++) s += sc[hl][i][j] * vs[j][cc];
        const int ti = i / WS, tj = i % WS;
        const size_t g = ((size_t)(b * 4096 + (p * WS + ti) * 64 + (q * WS + tj))) * 256 + h0 * 32 + cc;
        ushort hh, ll; split2(s, hh, ll);
        CTXh[g] = hh; CTXl[g] = ll;
    }
}

// -------- edge conv phase 1 + fused x pre-split ----------------------------
// y[p][t] = sum_c x[p][c] * ew[c][t]; also emits x hi/lo planes (each lane
// owns 4 channels of its pixel -- split once, store 8B each).
__global__ __launch_bounds__(256) void edge_gemm9(
    const float* __restrict__ x, const float* __restrict__ ew, float* __restrict__ ytmp,
    ushort* __restrict__ Xh, ushort* __restrict__ Xl)
{
    __shared__ float wsm[2304];   // ew[c*9 + t]
    const int tid = threadIdx.x;
    for (int i = tid; i < 2304; i += 256) wsm[i] = ew[i];
    __syncthreads();
    const int wave = tid >> 6, lane = tid & 63;
    const int p = blockIdx.x * 4 + wave;            // pixel index 0..65535
    const float4 xv = *(const float4*)(x + (size_t)p * 256 + lane * 4);
    {
        ushort4 h4, l4;
        split2(xv.x, h4.x, l4.x); split2(xv.y, h4.y, l4.y);
        split2(xv.z, h4.z, l4.z); split2(xv.w, h4.w, l4.w);
        *(ushort4*)(Xh + (size_t)p * 256 + lane * 4) = h4;
        *(ushort4*)(Xl + (size_t)p * 256 + lane * 4) = l4;
    }
    float acc[9];
#pragma unroll
    for (int t = 0; t < 9; t++) acc[t] = 0.f;
    const float xs[4] = {xv.x, xv.y, xv.z, xv.w};
#pragma unroll
    for (int i = 0; i < 4; i++) {
        const int c = lane * 4 + i;
#pragma unroll
        for (int t = 0; t < 9; t++)
            acc[t] = fmaf(xs[i], wsm[c * 9 + t], acc[t]);
    }
#pragma unroll
    for (int t = 0; t < 9; t++) {
#pragma unroll
        for (int off = 1; off < 64; off <<= 1)
            acc[t] += __shfl_xor(acc[t], off);
    }
    if (lane < 9) {
        float v = acc[0];
        switch (lane) {
            case 1: v = acc[1]; break; case 2: v = acc[2]; break;
            case 3: v = acc[3]; break; case 4: v = acc[4]; break;
            case 5: v = acc[5]; break; case 6: v = acc[6]; break;
            case 7: v = acc[7]; break; case 8: v = acc[8]; break;
            default: break;
        }
        ytmp[(size_t)p * 9 + lane] = v;
    }
}

// -------- edge conv phase 2: edge[h,w] = |sum_t y[h+dh,w+dw][t]| ------------
__global__ __launch_bounds__(256) void edge_combine(
    const float* __restrict__ ytmp, float* __restrict__ edge)
{
    const int idx = blockIdx.x * 256 + threadIdx.x;   // 0..65535
    const int b = idx >> 12, rem = idx & 4095, h = rem >> 6, w = rem & 63;
    float s = 0.f;
#pragma unroll
    for (int kh = 0; kh < 3; kh++) {
        const int hh = h + kh - 1;
        if ((unsigned)hh > 63u) continue;
#pragma unroll
        for (int kw = 0; kw < 3; kw++) {
            const int ww = w + kw - 1;
            if ((unsigned)ww > 63u) continue;
            s += ytmp[((size_t)b * 4096 + hh * 64 + ww) * 9 + kh * 3 + kw];
        }
    }
    edge[idx] = fabsf(s);
}

// ---------------- box-average + tiny MLP + 3-way softmax --------------------
__global__ __launch_bounds__(256) void avg_mlp(
    const float* __restrict__ edge, const float* __restrict__ w1, const float* __restrict__ b1,
    const float* __restrict__ w2, const float* __restrict__ b2, float* __restrict__ wts)
{
    const int idx = blockIdx.x * 256 + threadIdx.x;  // 0..65535
    const int b = idx >> 12, rem = idx & 4095, h = rem >> 6, w = rem & 63;
    float s = 0.f;
#pragma unroll
    for (int kh = -1; kh <= 1; kh++) {
        const int hh = h + kh;
        if ((unsigned)hh > 63u) continue;
#pragma unroll
        for (int kw = -1; kw <= 1; kw++) {
            const int ww = w + kw;
            if ((unsigned)ww > 63u) continue;
            s += edge[(size_t)b * 4096 + hh * 64 + ww];
        }
    }
    const float e = s / 9.f;
    float l0 = b2[0], l1 = b2[1], l2 = b2[2];
#pragma unroll
    for (int j = 0; j < 16; j++) {
        float hd = fmaxf(e * w1[j] + b1[j], 0.f);
        l0 += hd * w2[j * 3 + 0];
        l1 += hd * w2[j * 3 + 1];
        l2 += hd * w2[j * 3 + 2];
    }
    const float mx = fmaxf(l0, fmaxf(l1, l2));
    const float e0 = __expf(l0 - mx), e1 = __expf(l1 - mx), e2 = __expf(l2 - mx);
    const float inv = 1.f / (e0 + e1 + e2);
    wts[(size_t)idx * 3 + 0] = e0 * inv;
    wts[(size_t)idx * 3 + 1] = e1 * inv;
    wts[(size_t)idx * 3 + 2] = e2 * inv;
}

// ---------------------- DlightConv token pooling ----------------------------
// Emits xdl pre-split (hi/lo) for the axial gemm3.
__global__ __launch_bounds__(256) void dlight(
    const float* __restrict__ S1, const float* __restrict__ dlw,
    const float* __restrict__ dlb, ushort* __restrict__ XDLH, ushort* __restrict__ XDLL)
{
    __shared__ float xw[16][257];
    __shared__ float m[256];
    __shared__ float pr[16];
    __shared__ float pr2[16];
    const int wid = blockIdx.x;  // b*256 + p*16 + q
    const int b = wid >> 8, rem = wid & 255, p = rem >> 4, q = rem & 15;
    const int tid = threadIdx.x;  // channel
#pragma unroll
    for (int t = 0; t < 16; t++) {
        const int ti = t >> 2, tj = t & 3;
        xw[t][tid] = S1[((size_t)b * 4096 + (p * 4 + ti) * 64 + (q * 4 + tj)) * 256 + tid];
    }
    float mm = 0.f;
#pragma unroll
    for (int t = 0; t < 16; t++) mm += xw[t][tid];
    m[tid] = mm * (1.f / 16.f);
    __syncthreads();
    if (tid < 16) {
        float lg = dlb[tid];
        for (int c = 0; c < 256; c++) lg += m[c] * dlw[c * 16 + tid];
        pr[tid] = lg;
    }
    __syncthreads();
    if (tid < 16) {
        float mx = -3.4e38f;
        for (int j = 0; j < 16; j++) mx = fmaxf(mx, pr[j]);
        float sum = 0.f;
        for (int j = 0; j < 16; j++) sum += __expf(pr[j] - mx);
        pr2[tid] = __expf(pr[tid] - mx) / sum;
    }
    __syncthreads();
    float o = 0.f;
#pragma unroll
    for (int t = 0; t < 16; t++) o += xw[t][tid] * pr2[t];
    ushort hh, ll; split2(o, hh, ll);
    XDLH[(size_t)wid * 256 + tid] = hh;
    XDLL[(size_t)wid * 256 + tid] = ll;
}

// ----------------------------- axial attention ------------------------------
__global__ __launch_bounds__(256) void axial_row(
    const float* __restrict__ Q, const float* __restrict__ K, const float* __restrict__ V,
    const float* __restrict__ gsp, const float* __restrict__ gbp, float* __restrict__ XG)
{
    __shared__ float qs[16][257], ks[16][257], vs[16][257];
    __shared__ float sc[16][17];
    const int bid = blockIdx.x;
    const int b = bid >> 4, r = bid & 15;
    const int tid = threadIdx.x;
    const float gs = gsp[0], gb = gbp[0];
#pragma unroll
    for (int w = 0; w < 16; w++) {
        const size_t base = ((size_t)b * 256 + r * 16 + w) * 256 + tid;
        qs[w][tid] = Q[base]; ks[w][tid] = K[base]; vs[w][tid] = V[base];
    }
    __syncthreads();
    {
        const int w = tid >> 4, vv = tid & 15;
        float s = 0.f;
        for (int c = 0; c < 256; c++) s += qs[w][c] * ks[vv][c];
        const float d = (float)(w - vv);
        sc[w][vv] = s - (gs * d * d + gb);
    }
    __syncthreads();
    if (tid < 16) {
        float mx = -3.4e38f;
        for (int j = 0; j < 16; j++) mx = fmaxf(mx, sc[tid][j]);
        float sum = 0.f;
        for (int j = 0; j < 16; j++) {
            float e = __expf(sc[tid][j] - mx);
            sc[tid][j] = e; sum += e;
        }
        const float inv = 1.f / sum;
        for (int j = 0; j < 16; j++) sc[tid][j] *= inv;
    }
    __syncthreads();
#pragma unroll
    for (int w2 = 0; w2 < 16; w2++) {
        float o = 0.f;
#pragma unroll
        for (int k2 = 0; k2 < 16; k2++) o += sc[w2][k2] * vs[k2][tid];
        XG[((size_t)b * 256 + r * 16 + w2) * 256 + tid] = o;
    }
}

__global__ __launch_bounds__(256) void axial_col(
    const float* __restrict__ Q, const float* __restrict__ K, const float* __restrict__ V,
    const float* __restrict__ gsp, const float* __restrict__ gbp, float* __restrict__ XG)
{
    __shared__ float qs[16][257], ks[16][257], vs[16][257];
    __shared__ float sc[16][17];
    const int bid = blockIdx.x;
    const int b = bid >> 4, col = bid & 15;
    const int tid = threadIdx.x;
    const float gs = gsp[0], gb = gbp[0];
#pragma unroll
    for (int h = 0; h < 16; h++) {
        const size_t base = ((size_t)b * 256 + h * 16 + col) * 256 + tid;
        qs[h][tid] = Q[base]; ks[h][tid] = K[base]; vs[h][tid] = V[base];
    }
    __syncthreads();
    {
        const int r = tid >> 4, vv = tid & 15;
        float s = 0.f;
        for (int c = 0; c < 256; c++) s += qs[r][c] * ks[vv][c];
        const float d = (float)(r - vv);
        sc[r][vv] = s - (gs * d * d + gb);
    }
    __syncthreads();
    if (tid < 16) {
        float mx = -3.4e38f;
        for (int j = 0; j < 16; j++) mx = fmaxf(mx, sc[tid][j]);
        float sum = 0.f;
        for (int j = 0; j < 16; j++) {
            float e = __expf(sc[tid][j] - mx);
            sc[tid][j] = e; sum += e;
        }
        const float inv = 1.f / sum;
        for (int j = 0; j < 16; j++) sc[tid][j] *= inv;
    }
    __syncthreads();
#pragma unroll
    for (int r2 = 0; r2 < 16; r2++) {
        float o = 0.f;
#pragma unroll
        for (int k2 = 0; k2 < 16; k2++) o += sc[r2][k2] * vs[k2][tid];
        XG[((size_t)b * 256 + r2 * 16 + col) * 256 + tid] += o;
    }
}

// -------------------- bilinear upsample 16x16 -> 64x64 ----------------------
// Emits split hi/lo so gemmf's UP half stages A async.
__global__ __launch_bounds__(256) void upsample(
    const float* __restrict__ XG, ushort* __restrict__ UPH, ushort* __restrict__ UPL)
{
    const unsigned idx = blockIdx.x * 256u + threadIdx.x;
    const int c = idx & 255;
    const unsigned t2 = idx >> 8;
    const int w = t2 & 63;
    const unsigned t3 = t2 >> 6;
    const int h = t3 & 63;
    const int b = t3 >> 6;
    const float rr = 15.f / 63.f;
    const float ph = h * rr, pw = w * rr;
    int h0 = (int)floorf(ph); float th = ph - (float)h0; int h1 = min(h0 + 1, 15);
    int w0 = (int)floorf(pw); float tw = pw - (float)w0; int w1 = min(w0 + 1, 15);
    const size_t bb = (size_t)b * 256;
    const float v00 = XG[((bb + h0 * 16 + w0)) * 256 + c];
    const float v10 = XG[((bb + h1 * 16 + w0)) * 256 + c];
    const float v01 = XG[((bb + h0 * 16 + w1)) * 256 + c];
    const float v11 = XG[((bb + h1 * 16 + w1)) * 256 + c];
    const float c0 = v00 * (1.f - th) + v10 * th;
    const float c1 = v01 * (1.f - th) + v11 * th;
    const float val = c0 * (1.f - tw) + c1 * tw;
    ushort hh, ll; split2(val, hh, ll);
    UPH[idx] = hh; UPL[idx] = ll;
}

// ---------------------------------------------------------------------------
extern "C" void kernel_launch(void* const* d_in, const int* in_sizes, int n_in,
                              void* d_out, int out_size, void* d_ws, size_t ws_size,
                              hipStream_t stream)
{
    const float* x      = (const float*)d_in[0];
    const float* attn_w = (const float*)d_in[1];
    const float* attn_b = (const float*)d_in[2];
    const float* edge_w = (const float*)d_in[3];
    const float* mlp_w1 = (const float*)d_in[4];
    const float* mlp_b1 = (const float*)d_in[5];
    const float* mlp_w2 = (const float*)d_in[6];
    const float* mlp_b2 = (const float*)d_in[7];
    const float* dl_w   = (const float*)d_in[8];
    const float* dl_b   = (const float*)d_in[9];
    const float* ax_w   = (const float*)d_in[10];
    const float* ax_b   = (const float*)d_in[11];
    const float* g_shift= (const float*)d_in[12];
    const float* g_bias = (const float*)d_in[13];
    const float* sq_w   = (const float*)d_in[14];
    const float* sq_b   = (const float*)d_in[15];
    float* out = (float*)d_out;

    float* ws = (float*)d_ws;
    const size_t MT = 65536;
    float* blend = ws;                       // 16,777,216 floats
    float* s1    = blend + MT * 256;         // 16,777,216
    float* scr   = s1 + MT * 256;            // 16,777,216 (ytmp / chunk QKV+ctx / up)
    float* chQ   = scr;
    float* chK   = chQ + (size_t)CHUNK_TOK * 256;
    float* chV   = chK + (size_t)CHUNK_TOK * 256;
    ushort* ctxh = (ushort*)(chV + (size_t)CHUNK_TOK * 256);  // 4,194,304 ushorts
    ushort* ctxl = ctxh + (size_t)CHUNK_TOK * 256;            // 4,194,304 ushorts
    // ctxl ends exactly at scr + MT*256 floats (12.58M + 2*2.10M = 16.77M)
    ushort* uph  = (ushort*)scr;             // 16,777,216 ushorts (chunk bufs dead)
    ushort* upl  = uph + MT * 256;           // 16,777,216 ushorts
    float* ytmp  = scr;                      // 589,824 floats, dead before chQ use
    float* edge  = scr + MT * 256;           // 65,536
    float* wts   = edge + 65536;             // 196,608
    float* xdl   = wts + 196608;             // 1,048,576 floats region
    ushort* xdlh = (ushort*)xdl;             // 1,048,576 ushorts (2 MB)
    ushort* xdll = xdlh + 1048576;           // 1,048,576 ushorts (2 MB)
    float* axq   = xdl + 1048576;
    float* axk   = axq + 1048576;
    float* axv   = axk + 1048576;
    float* xg    = axv + 1048576;
    ushort* Wth = (ushort*)(xg + 1048576);
    ushort* Wtl = Wth + 1114112;
    // x hi/lo planes live in d_out (dead until gemmf writes it at the end)
    ushort* xh = (ushort*)out;               // 16,777,216 ushorts (32 MB)
    ushort* xl = xh + MT * 256;              // 16,777,216 ushorts (32 MB)

    // ---- pre-split weights: [n][k] bf16 hi/lo -----------------------------
    split_w_kmajor<<<(12 * 65536 + 255) / 256, 256, 0, stream>>>(attn_w, Wth, Wtl, 12);
    split_w_kmajor<<<(3 * 65536 + 255) / 256, 256, 0, stream>>>(
        ax_w, Wth + (size_t)12 * 65536, Wtl + (size_t)12 * 65536, 3);
    split_w_nmajor<<<(131072 + 255) / 256, 256, 0, stream>>>(
        sq_w, Wth + (size_t)15 * 65536, Wtl + (size_t)15 * 65536, 131072);

    // ---- selector weights (factorized edge conv) + fused x pre-split ------
    edge_gemm9<<<16384, 256, 0, stream>>>(x, edge_w, ytmp, xh, xl);
    edge_combine<<<256, 256, 0, stream>>>(ytmp, edge);
    avg_mlp<<<256, 256, 0, stream>>>(edge, mlp_w1, mlp_b1, mlp_w2, mlp_b2, wts);

    // ---- three window-attention scales, chunked; blend fused in proj ------
    for (int i = 0; i < 3; i++) {
        const ushort* Wh = Wth + (size_t)i * 4 * 65536;
        const ushort* Wl = Wtl + (size_t)i * 4 * 65536;
        const float* c0 = attn_b + (size_t)(i * 4 + 0) * 256;
        const float* c1 = attn_b + (size_t)(i * 4 + 1) * 256;
        const float* c2 = attn_b + (size_t)(i * 4 + 2) * 256;
        const float* c3 = attn_b + (size_t)(i * 4 + 3) * 256;
        for (int ch = 0; ch < 16 / CHUNK_B; ch++) {
            const size_t toff = (size_t)ch * CHUNK_TOK;
            gemm3_mfma<<<dim3(CHUNK_TOK / 128, 6), 256, 0, stream>>>(
                xh + toff * 256, xl + toff * 256, Wh, Wl, c0, c1, c2, chQ, chK, chV);
            if (i == 0)
                win_attn<2, 8><<<dim3(CHUNK_B * 32 * 32, 1), 256, 0, stream>>>(chQ, chK, chV, ctxh, ctxl);
            if (i == 1)
                win_attn<4, 4><<<dim3(CHUNK_B * 16 * 16, 2), 256, 0, stream>>>(chQ, chK, chV, ctxh, ctxl);
            if (i == 2)
                win_attn<8, 1><<<dim3(CHUNK_B * 8 * 8, 8), 256, 0, stream>>>(chQ, chK, chV, ctxh, ctxl);
            gemmp_mfma<<<dim3(CHUNK_TOK / 128, 2), 256, 0, stream>>>(
                ctxh, ctxl, Wh + (size_t)3 * 65536, Wl + (size_t)3 * 65536, c3,
                s1, (i == 1) ? 1 : 0, blend, wts, i, (i == 0) ? 1 : 0, (int)toff);
        }
    }

    // ---- DlightConv pooling on s1 (emits pre-split xdl) -------------------
    dlight<<<4096, 256, 0, stream>>>(s1, dl_w, dl_b, xdlh, xdll);

    // ---- axial q,k,v projections (M = 4096) -------------------------------
    gemm3_mfma<<<dim3(4096 / 128, 6), 256, 0, stream>>>(
        xdlh, xdll, Wth + (size_t)12 * 65536, Wtl + (size_t)12 * 65536,
        ax_b, ax_b + 256, ax_b + 512, axq, axk, axv);
    axial_row<<<256, 256, 0, stream>>>(axq, axk, axv, g_shift, g_bias, xg);
    axial_col<<<256, 256, 0, stream>>>(axq, axk, axv, g_shift, g_bias, xg);

    // ---- upsample 16x16 -> 64x64, pre-split, into reused scr region -------
    upsample<<<65536, 256, 0, stream>>>(xg, uph, upl);

    // ---- final squeeze GEMM (K=512) ---------------------------------------
    gemmf_mfma<<<dim3(512, 2), 256, 0, stream>>>(
        uph, upl, blend, Wth + (size_t)15 * 65536, Wtl + (size_t)15 * 65536, sq_b, out);
}

// Round 5
// 1281.765 us; speedup vs baseline: 1.0818x; 1.0145x over previous
//
#include <hip/hip_runtime.h>
#include <math.h>

// ---------------------------------------------------------------------------
// CSAttention forward, MI355X. GEMMs via split-bf16 (hi/lo) 3-MFMA emulation:
//   A*B ~= Ah*Bh + Al*Bh + Ah*Bl   (fp32 accumulate, ~16 mantissa bits)
// Layout: token maps (b, h*64+w, c) row-major, C=256, B=16.
// R6-R9 ladder (gemmf): reg+padded 70 | gload 79 | dbuf-gload 73 | reg-unpad 89
//   | gload+swizzle 80 (conflicts 0!). Attribution: register-destined loads
//   pipeline across the barrier; gload_lds can't. Swizzle is correct & free.
// R10: (a) register staging with the R9 swizzle mapping (identical LDS image,
//      GEMM_COMPUTE untouched): per K-step  sync -> ds_write(t) -> sync ->
//      issue loads(t+1) -> MFMA(t)  so load latency drains under compute;
//      (b) loop reorder chunks-outer/scales-inner: blend RMW + x re-reads
//      become L3-resident (reuse distance ~80 MB instead of ~800 MB).
// ---------------------------------------------------------------------------

#define CHUNK_B 4
#define CHUNK_TOK (CHUNK_B * 4096)   // 16384 tokens per chunk
#define KS 32                        // LDS k-slice width (elements), 64B rows

typedef __attribute__((ext_vector_type(8))) short short8;
typedef __attribute__((ext_vector_type(8))) unsigned short ushort8;
typedef __attribute__((ext_vector_type(4))) float f32x4;

__device__ __forceinline__ ushort f2bf(float f) {
    union { float f; unsigned u; } v; v.f = f;
    unsigned r = v.u + 0x7fff + ((v.u >> 16) & 1);
    return (ushort)(r >> 16);
}
__device__ __forceinline__ float bf2f(ushort h) {
    union { unsigned u; float f; } v; v.u = ((unsigned)h) << 16; return v.f;
}
__device__ __forceinline__ void split2(float v, ushort& h, ushort& l) {
    h = f2bf(v);
    l = f2bf(v - bf2f(h));
}

// ---------------- weight pre-split kernels ---------------------------------
__global__ __launch_bounds__(256) void split_w_kmajor(
    const float* __restrict__ W, ushort* __restrict__ Th, ushort* __restrict__ Tl, int nmats)
{
    const int idx = blockIdx.x * 256 + threadIdx.x;
    if (idx >= nmats * 65536) return;
    const int mat = idx >> 16, r = idx & 65535;
    const int n = r >> 8, k = r & 255;
    const float v = W[(size_t)mat * 65536 + k * 256 + n];
    ushort h, l; split2(v, h, l);
    Th[idx] = h; Tl[idx] = l;
}
__global__ __launch_bounds__(256) void split_w_nmajor(
    const float* __restrict__ W, ushort* __restrict__ Th, ushort* __restrict__ Tl, int total)
{
    const int idx = blockIdx.x * 256 + threadIdx.x;
    if (idx >= total) return;
    ushort h, l; split2(W[idx], h, l);
    Th[idx] = h; Tl[idx] = l;
}

// ---------------- MFMA GEMM core pieces (macros for reuse) -----------------
#define GEMM_DECLS                                                            \
    __shared__ ushort Ah[128 * KS], Al[128 * KS], Bh[128 * KS], Bl[128 * KS]; \
    const int tid = threadIdx.x;                                              \
    const int wave = tid >> 6, lane = tid & 63;                               \
    const int quad = lane >> 4, l16 = lane & 15;                              \
    const int wr = (wave >> 1) * 64, wc = (wave & 1) * 64;                    \
    f32x4 acc[4][4];                                                          \
    _Pragma("unroll") for (int i = 0; i < 4; i++)                             \
        _Pragma("unroll") for (int j = 0; j < 4; j++)                         \
            acc[i][j] = (f32x4){0.f, 0.f, 0.f, 0.f};

// Register staging of pre-split ushort planes, R9 swizzle mapping:
// thread owns LDS chunks {tid, tid+256}; chunk ch -> row ch>>2, LINEAR dest
// slot ch*16B; the GLOBAL source k-chunk is (ch&3)^((row>>1)&3) (involution).
// LDS image is byte-identical to R9's gload version -> GEMM_COMPUTE reuse.
#define LD_US(reg, src, strideE, rowbase, k0e)                                \
    _Pragma("unroll") for (int cc = 0; cc < 2; cc++) {                        \
        const int ch_ = tid + cc * 256;                                       \
        const int r_ = ch_ >> 2;                                              \
        const int kq_ = (ch_ & 3) ^ ((r_ >> 1) & 3);                          \
        reg[cc] = *(const ushort8*)((src) +                                   \
            (size_t)((rowbase) + r_) * (strideE) + (k0e) + (kq_ << 3));       \
    }
#define WR_US(dst, reg)                                                       \
    _Pragma("unroll") for (int cc = 0; cc < 2; cc++) {                        \
        *(ushort8*)&(dst)[(tid + cc * 256) * 8] = reg[cc];                    \
    }

// fp32 A staging (gemmf BLD half): raw float4 loads at issue time; split2 is
// deferred to the write phase so no VALU chain sits between issue and MFMA.
#define LD_F32(Aptr, kk)                                                      \
    {                                                                         \
        const int r0_ = tid >> 2, kc_ = (tid & 3) * 8;                        \
        const float* p0 = (Aptr) + (size_t)(m0 + r0_) * 256 + (kk) + kc_;     \
        const float* p1 = p0 + (size_t)64 * 256;                              \
        va[0] = *(const float4*)p0; va[1] = *(const float4*)(p0 + 4);         \
        va[2] = *(const float4*)p1; va[3] = *(const float4*)(p1 + 4);         \
    }
#define WR_F32(AhD, AlD)                                                      \
    _Pragma("unroll") for (int cc = 0; cc < 2; cc++) {                        \
        const int r_ = (tid >> 2) + cc * 64;                                  \
        const int kq_ = tid & 3;                                              \
        const int wsl_ = (kq_ ^ ((r_ >> 1) & 3)) << 3;                        \
        const float4 v0 = va[cc * 2], v1 = va[cc * 2 + 1];                    \
        ushort8 h, l; ushort hh, ll;                                          \
        split2(v0.x, hh, ll); h[0] = hh; l[0] = ll;                           \
        split2(v0.y, hh, ll); h[1] = hh; l[1] = ll;                           \
        split2(v0.z, hh, ll); h[2] = hh; l[2] = ll;                           \
        split2(v0.w, hh, ll); h[3] = hh; l[3] = ll;                           \
        split2(v1.x, hh, ll); h[4] = hh; l[4] = ll;                           \
        split2(v1.y, hh, ll); h[5] = hh; l[5] = ll;                           \
        split2(v1.z, hh, ll); h[6] = hh; l[6] = ll;                           \
        split2(v1.w, hh, ll); h[7] = hh; l[7] = ll;                           \
        *(ushort8*)&(AhD)[r_ * KS + wsl_] = h;                                \
        *(ushort8*)&(AlD)[r_ * KS + wsl_] = l;                                \
    }

// Fragment reads XOR the same swizzle: slot = quad ^ ((l16>>1)&3).
#define GEMM_COMPUTE                                                          \
    {                                                                         \
        const int aswz = (l16 & 6) << 2;  /* ((l16>>1)&3)*8 */                \
        short8 afh[4], afl[4], bfh[4], bfl[4];                                \
        _Pragma("unroll") for (int i = 0; i < 4; i++) {                       \
            const int ro = (wr + i * 16 + l16) * KS + ((quad * 8) ^ aswz);    \
            afh[i] = *(const short8*)&Ah[ro];                                 \
            afl[i] = *(const short8*)&Al[ro];                                 \
        }                                                                     \
        _Pragma("unroll") for (int j = 0; j < 4; j++) {                       \
            const int no = (wc + j * 16 + l16) * KS + ((quad * 8) ^ aswz);    \
            bfh[j] = *(const short8*)&Bh[no];                                 \
            bfl[j] = *(const short8*)&Bl[no];                                 \
        }                                                                     \
        _Pragma("unroll") for (int i = 0; i < 4; i++)                         \
            _Pragma("unroll") for (int j = 0; j < 4; j++) {                   \
                acc[i][j] = __builtin_amdgcn_mfma_f32_16x16x32_bf16(          \
                    afh[i], bfh[j], acc[i][j], 0, 0, 0);                      \
                acc[i][j] = __builtin_amdgcn_mfma_f32_16x16x32_bf16(          \
                    afl[i], bfh[j], acc[i][j], 0, 0, 0);                      \
                acc[i][j] = __builtin_amdgcn_mfma_f32_16x16x32_bf16(          \
                    afh[i], bfl[j], acc[i][j], 0, 0, 0);                      \
            }                                                                 \
    }

// ---------- fused 3-matrix GEMM (Q,K,V or axial q,k,v): grid (M/128, 6) -----
__global__ __launch_bounds__(256, 2) void gemm3_mfma(
    const ushort* __restrict__ AgH, const ushort* __restrict__ AgL,
    const ushort* __restrict__ Wth, const ushort* __restrict__ Wtl,
    const float* __restrict__ b0, const float* __restrict__ b1, const float* __restrict__ b2,
    float* __restrict__ O0, float* __restrict__ O1, float* __restrict__ O2)
{
    const int m0 = blockIdx.x * 128;
    const int mat = blockIdx.y >> 1;
    const int col0 = (blockIdx.y & 1) * 128;
    const ushort* wth = Wth + (size_t)mat * 65536 + (size_t)col0 * 256;
    const ushort* wtl = Wtl + (size_t)mat * 65536 + (size_t)col0 * 256;
    GEMM_DECLS
    ushort8 raH[2], raL[2], rbH[2], rbL[2];
    LD_US(raH, AgH, 256, m0, 0)
    LD_US(raL, AgL, 256, m0, 0)
    LD_US(rbH, wth, 256, 0, 0)
    LD_US(rbL, wtl, 256, 0, 0)
#pragma unroll
    for (int t = 0; t < 8; ++t) {
        __syncthreads();                      // previous compute done reading
        WR_US(Ah, raH) WR_US(Al, raL)
        WR_US(Bh, rbH) WR_US(Bl, rbL)
        __syncthreads();
        if (t < 7) {                          // issue next loads, then compute
            const int k1 = (t + 1) * 32;
            LD_US(raH, AgH, 256, m0, k1)
            LD_US(raL, AgL, 256, m0, k1)
            LD_US(rbH, wth, 256, 0, k1)
            LD_US(rbL, wtl, 256, 0, k1)
        }
        GEMM_COMPUTE
    }
    const float* bias = (mat == 0) ? b0 : (mat == 1) ? b1 : b2;
    float* O = (mat == 0) ? O0 : (mat == 1) ? O1 : O2;
#pragma unroll
    for (int j = 0; j < 4; j++) {
        const int col = col0 + wc + j * 16 + l16;
        const float bj = bias[col];
#pragma unroll
        for (int i = 0; i < 4; i++) {
            const int rbase = m0 + wr + i * 16 + quad * 4;
#pragma unroll
            for (int r = 0; r < 4; r++)
                O[(size_t)(rbase + r) * 256 + col] = acc[i][j][r] + bj;
        }
    }
}

// ---------- out-projection GEMM with fused blend: grid (M/128, 2) -----------
__global__ __launch_bounds__(256, 2) void gemmp_mfma(
    const ushort* __restrict__ AgH, const ushort* __restrict__ AgL,
    const ushort* __restrict__ Wth, const ushort* __restrict__ Wtl,
    const float* __restrict__ bias,
    float* __restrict__ Sout, int store_s,
    float* __restrict__ Blnd, const float* __restrict__ wts, int scale_idx, int blend_init,
    int row_off)
{
    const int m0 = blockIdx.x * 128;
    const int col0 = blockIdx.y * 128;
    const ushort* wth = Wth + (size_t)col0 * 256;
    const ushort* wtl = Wtl + (size_t)col0 * 256;
    GEMM_DECLS
    ushort8 raH[2], raL[2], rbH[2], rbL[2];
    LD_US(raH, AgH, 256, m0, 0)
    LD_US(raL, AgL, 256, m0, 0)
    LD_US(rbH, wth, 256, 0, 0)
    LD_US(rbL, wtl, 256, 0, 0)
#pragma unroll
    for (int t = 0; t < 8; ++t) {
        __syncthreads();
        WR_US(Ah, raH) WR_US(Al, raL)
        WR_US(Bh, rbH) WR_US(Bl, rbL)
        __syncthreads();
        if (t < 7) {
            const int k1 = (t + 1) * 32;
            LD_US(raH, AgH, 256, m0, k1)
            LD_US(raL, AgL, 256, m0, k1)
            LD_US(rbH, wth, 256, 0, k1)
            LD_US(rbL, wtl, 256, 0, k1)
        }
        GEMM_COMPUTE
    }
#pragma unroll
    for (int i = 0; i < 4; i++) {
        const int rbase = m0 + wr + i * 16 + quad * 4;
#pragma unroll
        for (int r = 0; r < 4; r++) {
            const size_t grow = (size_t)row_off + rbase + r;
            const float wt = wts[grow * 3 + scale_idx];
#pragma unroll
            for (int j = 0; j < 4; j++) {
                const int col = col0 + wc + j * 16 + l16;
                const float v = acc[i][j][r] + bias[col];
                if (store_s) Sout[grow * 256 + col] = v;
                float* bp = Blnd + grow * 256 + col;
                if (blend_init) *bp = wt * v;
                else            *bp = *bp + wt * v;
            }
        }
    }
}

// ---------- final squeeze: OUT = [UP | BL] @ sq_w^T + sq_b, K=512 -----------
// UP half pre-split ushort; BLD half fp32 with deferred split at write time.
__global__ __launch_bounds__(256, 2) void gemmf_mfma(
    const ushort* __restrict__ UPH, const ushort* __restrict__ UPL,
    const float* __restrict__ BLD,
    const ushort* __restrict__ Wth, const ushort* __restrict__ Wtl,
    const float* __restrict__ SQB, float* __restrict__ OUT)
{
    const int m0 = blockIdx.x * 128;
    const int col0 = blockIdx.y * 128;
    const ushort* wth = Wth + (size_t)col0 * 512;
    const ushort* wtl = Wtl + (size_t)col0 * 512;
    GEMM_DECLS
    ushort8 raH[2], raL[2], rbH[2], rbL[2];
    float4 va[4];
    LD_US(raH, UPH, 256, m0, 0)
    LD_US(raL, UPL, 256, m0, 0)
    LD_US(rbH, wth, 512, 0, 0)
    LD_US(rbL, wtl, 512, 0, 0)
#pragma unroll
    for (int t = 0; t < 16; ++t) {
        __syncthreads();
        if (t < 8) { WR_US(Ah, raH) WR_US(Al, raL) }
        else       { WR_F32(Ah, Al) }
        WR_US(Bh, rbH) WR_US(Bl, rbL)
        __syncthreads();
        if (t < 15) {
            const int k1 = (t + 1) * 32;
            LD_US(rbH, wth, 512, 0, k1)
            LD_US(rbL, wtl, 512, 0, k1)
            if (k1 < 256) {
                LD_US(raH, UPH, 256, m0, k1)
                LD_US(raL, UPL, 256, m0, k1)
            } else {
                LD_F32(BLD, (k1 & 255))
            }
        }
        GEMM_COMPUTE
    }
#pragma unroll
    for (int j = 0; j < 4; j++) {
        const int col = col0 + wc + j * 16 + l16;
        const float bj = SQB[col];
#pragma unroll
        for (int i = 0; i < 4; i++) {
            const int rbase = m0 + wr + i * 16 + quad * 4;
#pragma unroll
            for (int r = 0; r < 4; r++)
                OUT[(size_t)(rbase + r) * 256 + col] = acc[i][j][r] + bj;
        }
    }
}

// ----------------- windowed multi-head attention (per window) ---------------
template <int WS, int NH>
__global__ __launch_bounds__(256) void win_attn(
    const float* __restrict__ Q, const float* __restrict__ K,
    const float* __restrict__ V, ushort* __restrict__ CTXh, ushort* __restrict__ CTXl)
{
    constexpr int WIN = WS * WS;
    constexpr int NW = 64 / WS;
    constexpr int CW = NH * 32;
    __shared__ float qs[WIN][CW + 4], ks[WIN][CW + 4], vs[WIN][CW + 4];
    __shared__ float sc[NH][WIN][WIN + 1];
    const int tid = threadIdx.x;
    const int wid = blockIdx.x;
    const int b = wid / (NW * NW);
    const int rem = wid % (NW * NW);
    const int p = rem / NW, q = rem % NW;
    const int h0 = blockIdx.y * NH;

    for (int idx = tid; idx < WIN * CW; idx += 256) {
        const int i = idx / CW;
        const int cc = idx % CW;
        const int ti = i / WS, tj = i % WS;
        const size_t g = ((size_t)(b * 4096 + (p * WS + ti) * 64 + (q * WS + tj))) * 256 + h0 * 32 + cc;
        qs[i][cc] = Q[g]; ks[i][cc] = K[g]; vs[i][cc] = V[g];
    }
    __syncthreads();
    const float scale = 0.17677669529663687f;  // 1/sqrt(32)
    for (int idx = tid; idx < NH * WIN * WIN; idx += 256) {
        const int hl = idx / (WIN * WIN);
        const int r = idx % (WIN * WIN);
        const int i = r / WIN, j = r % WIN;
        const int co = hl * 32;
        float s = 0.f;
#pragma unroll
        for (int d = 0; d < 32; d++) s += qs[i][co + d] * ks[j][co + d];
        sc[hl][i][j] = s * scale;
    }
    __syncthreads();
    if (tid < NH * WIN) {
        const int hl = tid / WIN, i = tid % WIN;
        float mx = -3.4e38f;
        for (int j = 0; j < WIN; j++) mx = fmaxf(mx, sc[hl][i][j]);
        float sum = 0.f;
        for (int j = 0; j < WIN; j++) {
            float e = __expf(sc[hl][i][j] - mx);
            sc[hl][i][j] = e; sum += e;
        }
        const float inv = 1.f / sum;
        for (int j = 0; j < WIN; j++) sc[hl][i][j] *= inv;
    }
    __syncthreads();
    for (int idx = tid; idx < WIN * CW; idx += 256) {
        const int i = idx / CW;
        const int cc = idx % CW;
        const int hl = cc >> 5;
        float s = 0.f;
        for (int j = 0; j < WIN; j++) s += sc[hl][i][j] * vs[j][cc];
        const int ti = i / WS, tj = i % WS;
        const size_t g = ((size_t)(b * 4096 + (p * WS + ti) * 64 + (q * WS + tj))) * 256 + h0 * 32 + cc;
        ushort hh, ll; split2(s, hh, ll);
        CTXh[g] = hh; CTXl[g] = ll;
    }
}

// -------- edge conv phase 1 + fused x pre-split ----------------------------
__global__ __launch_bounds__(256) void edge_gemm9(
    const float* __restrict__ x, const float* __restrict__ ew, float* __restrict__ ytmp,
    ushort* __restrict__ Xh, ushort* __restrict__ Xl)
{
    __shared__ float wsm[2304];   // ew[c*9 + t]
    const int tid = threadIdx.x;
    for (int i = tid; i < 2304; i += 256) wsm[i] = ew[i];
    __syncthreads();
    const int wave = tid >> 6, lane = tid & 63;
    const int p = blockIdx.x * 4 + wave;            // pixel index 0..65535
    const float4 xv = *(const float4*)(x + (size_t)p * 256 + lane * 4);
    {
        ushort4 h4, l4;
        split2(xv.x, h4.x, l4.x); split2(xv.y, h4.y, l4.y);
        split2(xv.z, h4.z, l4.z); split2(xv.w, h4.w, l4.w);
        *(ushort4*)(Xh + (size_t)p * 256 + lane * 4) = h4;
        *(ushort4*)(Xl + (size_t)p * 256 + lane * 4) = l4;
    }
    float acc[9];
#pragma unroll
    for (int t = 0; t < 9; t++) acc[t] = 0.f;
    const float xs[4] = {xv.x, xv.y, xv.z, xv.w};
#pragma unroll
    for (int i = 0; i < 4; i++) {
        const int c = lane * 4 + i;
#pragma unroll
        for (int t = 0; t < 9; t++)
            acc[t] = fmaf(xs[i], wsm[c * 9 + t], acc[t]);
    }
#pragma unroll
    for (int t = 0; t < 9; t++) {
#pragma unroll
        for (int off = 1; off < 64; off <<= 1)
            acc[t] += __shfl_xor(acc[t], off);
    }
    if (lane < 9) {
        float v = acc[0];
        switch (lane) {
            case 1: v = acc[1]; break; case 2: v = acc[2]; break;
            case 3: v = acc[3]; break; case 4: v = acc[4]; break;
            case 5: v = acc[5]; break; case 6: v = acc[6]; break;
            case 7: v = acc[7]; break; case 8: v = acc[8]; break;
            default: break;
        }
        ytmp[(size_t)p * 9 + lane] = v;
    }
}

// -------- edge conv phase 2: edge[h,w] = |sum_t y[h+dh,w+dw][t]| ------------
__global__ __launch_bounds__(256) void edge_combine(
    const float* __restrict__ ytmp, float* __restrict__ edge)
{
    const int idx = blockIdx.x * 256 + threadIdx.x;   // 0..65535
    const int b = idx >> 12, rem = idx & 4095, h = rem >> 6, w = rem & 63;
    float s = 0.f;
#pragma unroll
    for (int kh = 0; kh < 3; kh++) {
        const int hh = h + kh - 1;
        if ((unsigned)hh > 63u) continue;
#pragma unroll
        for (int kw = 0; kw < 3; kw++) {
            const int ww = w + kw - 1;
            if ((unsigned)ww > 63u) continue;
            s += ytmp[((size_t)b * 4096 + hh * 64 + ww) * 9 + kh * 3 + kw];
        }
    }
    edge[idx] = fabsf(s);
}

// ---------------- box-average + tiny MLP + 3-way softmax --------------------
__global__ __launch_bounds__(256) void avg_mlp(
    const float* __restrict__ edge, const float* __restrict__ w1, const float* __restrict__ b1,
    const float* __restrict__ w2, const float* __restrict__ b2, float* __restrict__ wts)
{
    const int idx = blockIdx.x * 256 + threadIdx.x;  // 0..65535
    const int b = idx >> 12, rem = idx & 4095, h = rem >> 6, w = rem & 63;
    float s = 0.f;
#pragma unroll
    for (int kh = -1; kh <= 1; kh++) {
        const int hh = h + kh;
        if ((unsigned)hh > 63u) continue;
#pragma unroll
        for (int kw = -1; kw <= 1; kw++) {
            const int ww = w + kw;
            if ((unsigned)ww > 63u) continue;
            s += edge[(size_t)b * 4096 + hh * 64 + ww];
        }
    }
    const float e = s / 9.f;
    float l0 = b2[0], l1 = b2[1], l2 = b2[2];
#pragma unroll
    for (int j = 0; j < 16; j++) {
        float hd = fmaxf(e * w1[j] + b1[j], 0.f);
        l0 += hd * w2[j * 3 + 0];
        l1 += hd * w2[j * 3 + 1];
        l2 += hd * w2[j * 3 + 2];
    }
    const float mx = fmaxf(l0, fmaxf(l1, l2));
    const float e0 = __expf(l0 - mx), e1 = __expf(l1 - mx), e2 = __expf(l2 - mx);
    const float inv = 1.f / (e0 + e1 + e2);
    wts[(size_t)idx * 3 + 0] = e0 * inv;
    wts[(size_t)idx * 3 + 1] = e1 * inv;
    wts[(size_t)idx * 3 + 2] = e2 * inv;
}

// ---------------------- DlightConv token pooling ----------------------------
__global__ __launch_bounds__(256) void dlight(
    const float* __restrict__ S1, const float* __restrict__ dlw,
    const float* __restrict__ dlb, ushort* __restrict__ XDLH, ushort* __restrict__ XDLL)
{
    __shared__ float xw[16][257];
    __shared__ float m[256];
    __shared__ float pr[16];
    __shared__ float pr2[16];
    const int wid = blockIdx.x;  // b*256 + p*16 + q
    const int b = wid >> 8, rem = wid & 255, p = rem >> 4, q = rem & 15;
    const int tid = threadIdx.x;  // channel
#pragma unroll
    for (int t = 0; t < 16; t++) {
        const int ti = t >> 2, tj = t & 3;
        xw[t][tid] = S1[((size_t)b * 4096 + (p * 4 + ti) * 64 + (q * 4 + tj)) * 256 + tid];
    }
    float mm = 0.f;
#pragma unroll
    for (int t = 0; t < 16; t++) mm += xw[t][tid];
    m[tid] = mm * (1.f / 16.f);
    __syncthreads();
    if (tid < 16) {
        float lg = dlb[tid];
        for (int c = 0; c < 256; c++) lg += m[c] * dlw[c * 16 + tid];
        pr[tid] = lg;
    }
    __syncthreads();
    if (tid < 16) {
        float mx = -3.4e38f;
        for (int j = 0; j < 16; j++) mx = fmaxf(mx, pr[j]);
        float sum = 0.f;
        for (int j = 0; j < 16; j++) sum += __expf(pr[j] - mx);
        pr2[tid] = __expf(pr[tid] - mx) / sum;
    }
    __syncthreads();
    float o = 0.f;
#pragma unroll
    for (int t = 0; t < 16; t++) o += xw[t][tid] * pr2[t];
    ushort hh, ll; split2(o, hh, ll);
    XDLH[(size_t)wid * 256 + tid] = hh;
    XDLL[(size_t)wid * 256 + tid] = ll;
}

// ----------------------------- axial attention ------------------------------
__global__ __launch_bounds__(256) void axial_row(
    const float* __restrict__ Q, const float* __restrict__ K, const float* __restrict__ V,
    const float* __restrict__ gsp, const float* __restrict__ gbp, float* __restrict__ XG)
{
    __shared__ float qs[16][257], ks[16][257], vs[16][257];
    __shared__ float sc[16][17];
    const int bid = blockIdx.x;
    const int b = bid >> 4, r = bid & 15;
    const int tid = threadIdx.x;
    const float gs = gsp[0], gb = gbp[0];
#pragma unroll
    for (int w = 0; w < 16; w++) {
        const size_t base = ((size_t)b * 256 + r * 16 + w) * 256 + tid;
        qs[w][tid] = Q[base]; ks[w][tid] = K[base]; vs[w][tid] = V[base];
    }
    __syncthreads();
    {
        const int w = tid >> 4, vv = tid & 15;
        float s = 0.f;
        for (int c = 0; c < 256; c++) s += qs[w][c] * ks[vv][c];
        const float d = (float)(w - vv);
        sc[w][vv] = s - (gs * d * d + gb);
    }
    __syncthreads();
    if (tid < 16) {
        float mx = -3.4e38f;
        for (int j = 0; j < 16; j++) mx = fmaxf(mx, sc[tid][j]);
        float sum = 0.f;
        for (int j = 0; j < 16; j++) {
            float e = __expf(sc[tid][j] - mx);
            sc[tid][j] = e; sum += e;
        }
        const float inv = 1.f / sum;
        for (int j = 0; j < 16; j++) sc[tid][j] *= inv;
    }
    __syncthreads();
#pragma unroll
    for (int w2 = 0; w2 < 16; w2++) {
        float o = 0.f;
#pragma unroll
        for (int k2 = 0; k2 < 16; k2++) o += sc[w2][k2] * vs[k2][tid];
        XG[((size_t)b * 256 + r * 16 + w2) * 256 + tid] = o;
    }
}

__global__ __launch_bounds__(256) void axial_col(
    const float* __restrict__ Q, const float* __restrict__ K, const float* __restrict__ V,
    const float* __restrict__ gsp, const float* __restrict__ gbp, float* __restrict__ XG)
{
    __shared__ float qs[16][257], ks[16][257], vs[16][257];
    __shared__ float sc[16][17];
    const int bid = blockIdx.x;
    const int b = bid >> 4, col = bid & 15;
    const int tid = threadIdx.x;
    const float gs = gsp[0], gb = gbp[0];
#pragma unroll
    for (int h = 0; h < 16; h++) {
        const size_t base = ((size_t)b * 256 + h * 16 + col) * 256 + tid;
        qs[h][tid] = Q[base]; ks[h][tid] = K[base]; vs[h][tid] = V[base];
    }
    __syncthreads();
    {
        const int r = tid >> 4, vv = tid & 15;
        float s = 0.f;
        for (int c = 0; c < 256; c++) s += qs[r][c] * ks[vv][c];
        const float d = (float)(r - vv);
        sc[r][vv] = s - (gs * d * d + gb);
    }
    __syncthreads();
    if (tid < 16) {
        float mx = -3.4e38f;
        for (int j = 0; j < 16; j++) mx = fmaxf(mx, sc[tid][j]);
        float sum = 0.f;
        for (int j = 0; j < 16; j++) {
            float e = __expf(sc[tid][j] - mx);
            sc[tid][j] = e; sum += e;
        }
        const float inv = 1.f / sum;
        for (int j = 0; j < 16; j++) sc[tid][j] *= inv;
    }
    __syncthreads();
#pragma unroll
    for (int r2 = 0; r2 < 16; r2++) {
        float o = 0.f;
#pragma unroll
        for (int k2 = 0; k2 < 16; k2++) o += sc[r2][k2] * vs[k2][tid];
        XG[((size_t)b * 256 + r2 * 16 + col) * 256 + tid] += o;
    }
}

// -------------------- bilinear upsample 16x16 -> 64x64 ----------------------
__global__ __launch_bounds__(256) void upsample(
    const float* __restrict__ XG, ushort* __restrict__ UPH, ushort* __restrict__ UPL)
{
    const unsigned idx = blockIdx.x * 256u + threadIdx.x;
    const int c = idx & 255;
    const unsigned t2 = idx >> 8;
    const int w = t2 & 63;
    const unsigned t3 = t2 >> 6;
    const int h = t3 & 63;
    const int b = t3 >> 6;
    const float rr = 15.f / 63.f;
    const float ph = h * rr, pw = w * rr;
    int h0 = (int)floorf(ph); float th = ph - (float)h0; int h1 = min(h0 + 1, 15);
    int w0 = (int)floorf(pw); float tw = pw - (float)w0; int w1 = min(w0 + 1, 15);
    const size_t bb = (size_t)b * 256;
    const float v00 = XG[((bb + h0 * 16 + w0)) * 256 + c];
    const float v10 = XG[((bb + h1 * 16 + w0)) * 256 + c];
    const float v01 = XG[((bb + h0 * 16 + w1)) * 256 + c];
    const float v11 = XG[((bb + h1 * 16 + w1)) * 256 + c];
    const float c0 = v00 * (1.f - th) + v10 * th;
    const float c1 = v01 * (1.f - th) + v11 * th;
    const float val = c0 * (1.f - tw) + c1 * tw;
    ushort hh, ll; split2(val, hh, ll);
    UPH[idx] = hh; UPL[idx] = ll;
}

// ---------------------------------------------------------------------------
extern "C" void kernel_launch(void* const* d_in, const int* in_sizes, int n_in,
                              void* d_out, int out_size, void* d_ws, size_t ws_size,
                              hipStream_t stream)
{
    const float* x      = (const float*)d_in[0];
    const float* attn_w = (const float*)d_in[1];
    const float* attn_b = (const float*)d_in[2];
    const float* edge_w = (const float*)d_in[3];
    const float* mlp_w1 = (const float*)d_in[4];
    const float* mlp_b1 = (const float*)d_in[5];
    const float* mlp_w2 = (const float*)d_in[6];
    const float* mlp_b2 = (const float*)d_in[7];
    const float* dl_w   = (const float*)d_in[8];
    const float* dl_b   = (const float*)d_in[9];
    const float* ax_w   = (const float*)d_in[10];
    const float* ax_b   = (const float*)d_in[11];
    const float* g_shift= (const float*)d_in[12];
    const float* g_bias = (const float*)d_in[13];
    const float* sq_w   = (const float*)d_in[14];
    const float* sq_b   = (const float*)d_in[15];
    float* out = (float*)d_out;

    float* ws = (float*)d_ws;
    const size_t MT = 65536;
    float* blend = ws;                       // 16,777,216 floats
    float* s1    = blend + MT * 256;         // 16,777,216
    float* scr   = s1 + MT * 256;            // 16,777,216 (ytmp / chunk QKV+ctx / up)
    float* chQ   = scr;
    float* chK   = chQ + (size_t)CHUNK_TOK * 256;
    float* chV   = chK + (size_t)CHUNK_TOK * 256;
    ushort* ctxh = (ushort*)(chV + (size_t)CHUNK_TOK * 256);  // 4,194,304 ushorts
    ushort* ctxl = ctxh + (size_t)CHUNK_TOK * 256;            // 4,194,304 ushorts
    ushort* uph  = (ushort*)scr;             // 16,777,216 ushorts (chunk bufs dead)
    ushort* upl  = uph + MT * 256;           // 16,777,216 ushorts
    float* ytmp  = scr;                      // 589,824 floats, dead before chQ use
    float* edge  = scr + MT * 256;           // 65,536
    float* wts   = edge + 65536;             // 196,608
    float* xdl   = wts + 196608;             // 1,048,576 floats region
    ushort* xdlh = (ushort*)xdl;             // 1,048,576 ushorts (2 MB)
    ushort* xdll = xdlh + 1048576;           // 1,048,576 ushorts (2 MB)
    float* axq   = xdl + 1048576;
    float* axk   = axq + 1048576;
    float* axv   = axk + 1048576;
    float* xg    = axv + 1048576;
    ushort* Wth = (ushort*)(xg + 1048576);
    ushort* Wtl = Wth + 1114112;
    // x hi/lo planes live in d_out (dead until gemmf writes it at the end)
    ushort* xh = (ushort*)out;               // 16,777,216 ushorts (32 MB)
    ushort* xl = xh + MT * 256;              // 16,777,216 ushorts (32 MB)

    // ---- pre-split weights: [n][k] bf16 hi/lo -----------------------------
    split_w_kmajor<<<(12 * 65536 + 255) / 256, 256, 0, stream>>>(attn_w, Wth, Wtl, 12);
    split_w_kmajor<<<(3 * 65536 + 255) / 256, 256, 0, stream>>>(
        ax_w, Wth + (size_t)12 * 65536, Wtl + (size_t)12 * 65536, 3);
    split_w_nmajor<<<(131072 + 255) / 256, 256, 0, stream>>>(
        sq_w, Wth + (size_t)15 * 65536, Wtl + (size_t)15 * 65536, 131072);

    // ---- selector weights (factorized edge conv) + fused x pre-split ------
    edge_gemm9<<<16384, 256, 0, stream>>>(x, edge_w, ytmp, xh, xl);
    edge_combine<<<256, 256, 0, stream>>>(ytmp, edge);
    avg_mlp<<<256, 256, 0, stream>>>(edge, mlp_w1, mlp_b1, mlp_w2, mlp_b2, wts);

    // ---- three window-attention scales: CHUNKS OUTER, SCALES INNER --------
    // (blend RMW + x re-reads become L3-resident; deps are per-(ch,i), safe)
    for (int ch = 0; ch < 16 / CHUNK_B; ch++) {
        const size_t toff = (size_t)ch * CHUNK_TOK;
        for (int i = 0; i < 3; i++) {
            const ushort* Wh = Wth + (size_t)i * 4 * 65536;
            const ushort* Wl = Wtl + (size_t)i * 4 * 65536;
            const float* c0 = attn_b + (size_t)(i * 4 + 0) * 256;
            const float* c1 = attn_b + (size_t)(i * 4 + 1) * 256;
            const float* c2 = attn_b + (size_t)(i * 4 + 2) * 256;
            const float* c3 = attn_b + (size_t)(i * 4 + 3) * 256;
            gemm3_mfma<<<dim3(CHUNK_TOK / 128, 6), 256, 0, stream>>>(
                xh + toff * 256, xl + toff * 256, Wh, Wl, c0, c1, c2, chQ, chK, chV);
            if (i == 0)
                win_attn<2, 8><<<dim3(CHUNK_B * 32 * 32, 1), 256, 0, stream>>>(chQ, chK, chV, ctxh, ctxl);
            if (i == 1)
                win_attn<4, 4><<<dim3(CHUNK_B * 16 * 16, 2), 256, 0, stream>>>(chQ, chK, chV, ctxh, ctxl);
            if (i == 2)
                win_attn<8, 1><<<dim3(CHUNK_B * 8 * 8, 8), 256, 0, stream>>>(chQ, chK, chV, ctxh, ctxl);
            gemmp_mfma<<<dim3(CHUNK_TOK / 128, 2), 256, 0, stream>>>(
                ctxh, ctxl, Wh + (size_t)3 * 65536, Wl + (size_t)3 * 65536, c3,
                s1, (i == 1) ? 1 : 0, blend, wts, i, (i == 0) ? 1 : 0, (int)toff);
        }
    }

    // ---- DlightConv pooling on s1 (emits pre-split xdl) -------------------
    dlight<<<4096, 256, 0, stream>>>(s1, dl_w, dl_b, xdlh, xdll);

    // ---- axial q,k,v projections (M = 4096) -------------------------------
    gemm3_mfma<<<dim3(4096 / 128, 6), 256, 0, stream>>>(
        xdlh, xdll, Wth + (size_t)12 * 65536, Wtl + (size_t)12 * 65536,
        ax_b, ax_b + 256, ax_b + 512, axq, axk, axv);
    axial_row<<<256, 256, 0, stream>>>(axq, axk, axv, g_shift, g_bias, xg);
    axial_col<<<256, 256, 0, stream>>>(axq, axk, axv, g_shift, g_bias, xg);

    // ---- upsample 16x16 -> 64x64, pre-split, into reused scr region -------
    upsample<<<65536, 256, 0, stream>>>(xg, uph, upl);

    // ---- final squeeze GEMM (K=512) ---------------------------------------
    gemmf_mfma<<<dim3(512, 2), 256, 0, stream>>>(
        uph, upl, blend, Wth + (size_t)15 * 65536, Wtl + (size_t)15 * 65536, sq_b, out);
}